// Round 6
// baseline (380.589 us; speedup 1.0000x reference)
//
#include <hip/hip_runtime.h>
#include <hip/hip_bf16.h>
#include <stdint.h>

// Problem dims: B=16, C=512, H=W=32, NH=8, HC=64, HW=1024, 3C=1536
#define Bn  16
#define Cch 512
#define C3  1536
#define HWp 1024

typedef __attribute__((ext_vector_type(8))) short bf16x8;    // 8 bf16 = 4 VGPRs (MFMA A/B frag)
typedef __attribute__((ext_vector_type(4))) float f32x4;     // 16x16 MFMA C/D frag
typedef __attribute__((ext_vector_type(2))) float f32x2;     // packed pair for v_pk_fma_f32

#define DEV static __device__ __forceinline__

DEV float bflo(unsigned u) { return __builtin_bit_cast(float, u << 16); }
DEV float bfhi(unsigned u) { return __builtin_bit_cast(float, u & 0xffff0000u); }
DEV unsigned short f2bf(float f) {
  __hip_bfloat16 h = __float2bfloat16(f);
  return __builtin_bit_cast(unsigned short, h);
}
DEV f32x2 up2(unsigned u) { f32x2 r; r[0] = bflo(u); r[1] = bfhi(u); return r; }

// packed f32 FMA: d = a*b + d (both lanes). gfx90a+ VOP3P.
#define PKFMA(d, a, b) asm("v_pk_fma_f32 %0, %1, %2, %0" : "+v"(d) : "v"(a), "v"(b))

// async global->LDS, 16B per lane. LDS dest must be wave-uniform base + lane*16.
DEV void async16(__hip_bfloat16* lds, const __hip_bfloat16* g) {
  __builtin_amdgcn_global_load_lds(
      (const __attribute__((address_space(1))) unsigned*)g,
      (__attribute__((address_space(3))) unsigned*)lds, 16, 0, 0);
}

// ---------------- 1. weight prep (fp32->bf16, vectorized) + LayerNorm partial sums ----------------
// blocks [0,1536): pw-weight cast as float4->bf16x4 (393216 float4)
// blocks [1536,3584): proj transpose (scalar reads, coalesced writes)
// blocks [3584,5632): ln partial (2048 = t*1024 + b*64 + chunk)
__global__ __launch_bounds__(256) void k_prep_ln(
    const float* __restrict__ img_pw_w, const float* __restrict__ wm_pw_w,
    const float* __restrict__ proj,
    const float* __restrict__ image, const float* __restrict__ watermark,
    __hip_bfloat16* __restrict__ Wpw, __hip_bfloat16* __restrict__ projT,
    float* __restrict__ part)
{
  __shared__ float ls[4], lss[4];
  int blkid = blockIdx.x;
  if (blkid < 1536) {
    int i = blkid * 256 + threadIdx.x;      // float4 index, 0..393215
    const int NW4 = (C3 * Cch) / 4;         // 196608
    const float4* srcv = (i < NW4) ? (const float4*)img_pw_w : (const float4*)wm_pw_w;
    int j = (i < NW4) ? i : i - NW4;
    float4 v = srcv[j];
    ushort4 o = { f2bf(v.x), f2bf(v.y), f2bf(v.z), f2bf(v.w) };
    ((ushort4*)Wpw)[i] = o;
    return;
  }
  if (blkid < 3584) {
    int j = (blkid - 1536) * 256 + threadIdx.x;   // 0..524287
    int c = j >> 10, d = j & 1023;
    projT[(size_t)c * 1024 + d] = __float2bfloat16(proj[(size_t)d * 512 + c]);
    return;
  }
  int blk = blkid - 3584;
  int chunk = blk & 63, b = (blk >> 6) & 15, t = blk >> 10;
  const float* x = (t ? watermark : image) + (size_t)b * Cch * HWp + chunk * 8192;
  const float4* xv = (const float4*)x;
  float s = 0.f, ss = 0.f;
#pragma unroll
  for (int i = 0; i < 8; i++) {
    float4 v = xv[threadIdx.x + i * 256];
    s  += v.x + v.y + v.z + v.w;
    ss += v.x * v.x + v.y * v.y + v.z * v.z + v.w * v.w;
  }
#pragma unroll
  for (int off = 32; off; off >>= 1) { s += __shfl_down(s, off); ss += __shfl_down(ss, off); }
  int wv = threadIdx.x >> 6;
  if ((threadIdx.x & 63) == 0) { ls[wv] = s; lss[wv] = ss; }
  __syncthreads();
  if (threadIdx.x == 0) {
    part[blk * 2]     = ls[0] + ls[1] + ls[2] + ls[3];
    part[blk * 2 + 1] = lss[0] + lss[1] + lss[2] + lss[3];
  }
}

// ---------------- 4. normalize + affine + transpose -> xnT[t][b][p][c] bf16 ----------------
// (ln finalize folded in: wave 0 reduces this (t,b)'s 64 partial pairs)
__global__ __launch_bounds__(256) void k_norm_t(
    const float* __restrict__ image, const float* __restrict__ watermark,
    const float* __restrict__ img_w, const float* __restrict__ img_b,
    const float* __restrict__ wm_w,  const float* __restrict__ wm_b,
    const float* __restrict__ part, __hip_bfloat16* __restrict__ xnT)
{
  int blk = blockIdx.x;
  int ct = blk & 15, pt = (blk >> 4) & 15, b = (blk >> 8) & 15, t = blk >> 12;
  int c0 = ct * 32, p0 = pt * 64;
  const float* x   = (t ? watermark : image) + (size_t)b * Cch * HWp;
  const float* wgt = t ? wm_w : img_w;
  const float* bia = t ? wm_b : img_b;
  int tid = threadIdx.x;
  __shared__ float sst[2];
  if (tid < 64) {
    float S  = part[(t * 1024 + b * 64 + tid) * 2];
    float SS = part[(t * 1024 + b * 64 + tid) * 2 + 1];
#pragma unroll
    for (int off = 32; off; off >>= 1) { S += __shfl_down(S, off); SS += __shfl_down(SS, off); }
    if (tid == 0) {
      const float inv = 1.f / (float)(Cch * HWp);
      float mu  = S * inv;
      float var = SS * inv - mu * mu;
      sst[0] = mu;
      sst[1] = rsqrtf(var + 1e-5f);
    }
  }
  __syncthreads();
  float mu = sst[0], rstd = sst[1];
  __shared__ float tile[32 * 66];
  {
    int c = tid >> 3, s = tid & 7;
    const float* xr = x   + (size_t)(c0 + c) * HWp + p0;
    const float* wr = wgt + (size_t)(c0 + c) * HWp + p0;
    const float* br = bia + (size_t)(c0 + c) * HWp + p0;
#pragma unroll
    for (int j = 0; j < 2; j++) {
      int f = s + j * 8;                 // float4 slot 0..15
      float4 xv = *(const float4*)&xr[f * 4];
      float4 wv = *(const float4*)&wr[f * 4];
      float4 bv = *(const float4*)&br[f * 4];
      float n0 = (xv.x - mu) * rstd * wv.x + bv.x;
      float n1 = (xv.y - mu) * rstd * wv.y + bv.y;
      float n2 = (xv.z - mu) * rstd * wv.z + bv.z;
      float n3 = (xv.w - mu) * rstd * wv.w + bv.w;
      *(float2*)&tile[c * 66 + f * 4]     = make_float2(n0, n1);
      *(float2*)&tile[c * 66 + f * 4 + 2] = make_float2(n2, n3);
    }
  }
  __syncthreads();
  {
    int p = tid >> 2, cq = tid & 3;      // 64 p x 4 c-groups of 8
    union { unsigned short us[8]; uint4 v4; } pk;
#pragma unroll
    for (int j = 0; j < 8; j++) pk.us[j] = f2bf(tile[(cq * 8 + j) * 66 + p]);
    __hip_bfloat16* dst = xnT + ((size_t)(t * 16 + b)) * HWp * Cch
                        + (size_t)(p0 + p) * Cch + c0 + cq * 8;
    *(uint4*)dst = pk.v4;
  }
}

// ---------------- 5. bf16 BT-GEMM core: 16x16x32 MFMA + XOR-swizzled LDS ----------------
template<int MI, int Kdim, int Ncols, bool OBF, bool HB>
DEV void gemm_core(const __hip_bfloat16* __restrict__ A,
                   const __hip_bfloat16* __restrict__ Bt,
                   const float* __restrict__ bias, void* __restrict__ Cout, int m0)
{
  constexpr int MT = MI * 32;
  __shared__ __hip_bfloat16 As[MT * 64];
  __shared__ __hip_bfloat16 Bs[128 * 64];
  const int tid = threadIdx.x, lane = tid & 63, wv = tid >> 6;
  const int lr = lane & 15, lq = lane >> 4;
  const int wm = (wv >> 1) * (MI * 16), wn = (wv & 1) * 64;
  const int n0 = blockIdx.x * 128;
  f32x4 acc[MI][4] = {};
  const int srow = tid >> 3, sslot = tid & 7;
  const int sseg = (sslot ^ (srow & 7)) * 8;    // swizzled global segment (halfs)
  for (int k0 = 0; k0 < Kdim; k0 += 64) {
#pragma unroll
    for (int c = 0; c < MI; c++) {
      int row = srow + c * 32;                  // row&7 == srow&7 (c*32 mult of 8)
      async16(&As[row * 64 + sslot * 8], &A[(size_t)(m0 + row) * Kdim + k0 + sseg]);
    }
#pragma unroll
    for (int c = 0; c < 4; c++) {
      int row = srow + c * 32;
      async16(&Bs[row * 64 + sslot * 8], &Bt[(size_t)(n0 + row) * Kdim + k0 + sseg]);
    }
    __syncthreads();   // compiler emits vmcnt(0) drain here
#pragma unroll
    for (int ks = 0; ks < 2; ks++) {
      bf16x8 af[MI], bfr[4];
#pragma unroll
      for (int mi = 0; mi < MI; mi++) {
        int r = wm + mi * 16 + lr;              // r&7 == lr&7
        af[mi]  = *(const bf16x8*)&As[r * 64 + (((ks * 4 + lq) ^ (lr & 7)) * 8)];
      }
#pragma unroll
      for (int ni = 0; ni < 4; ni++) {
        int r = wn + ni * 16 + lr;
        bfr[ni] = *(const bf16x8*)&Bs[r * 64 + (((ks * 4 + lq) ^ (lr & 7)) * 8)];
      }
#pragma unroll
      for (int mi = 0; mi < MI; mi++)
#pragma unroll
        for (int ni = 0; ni < 4; ni++)
          acc[mi][ni] = __builtin_amdgcn_mfma_f32_16x16x32_bf16(af[mi], bfr[ni], acc[mi][ni], 0, 0, 0);
    }
    __syncthreads();
  }
#pragma unroll
  for (int mi = 0; mi < MI; mi++) {
    int mrow = m0 + wm + mi * 16 + lq * 4;
#pragma unroll
    for (int ni = 0; ni < 4; ni++) {
      int ncol = n0 + wn + ni * 16 + lr;
#pragma unroll
      for (int r = 0; r < 4; r++) {
        float y = acc[mi][ni][r];
        int row = mrow + r;
        if (HB) y += bias[row];
        if (OBF) ((__hip_bfloat16*)Cout)[(size_t)row * Ncols + ncol] = __float2bfloat16(y);
        else     ((float*)Cout)[(size_t)row * Ncols + ncol] = y;
      }
    }
  }
}

__global__ __launch_bounds__(256) void k_pw_gemm(
    const __hip_bfloat16* __restrict__ Wpw, const __hip_bfloat16* __restrict__ xnT,
    const float* __restrict__ img_pw_b, const float* __restrict__ wm_pw_b,
    __hip_bfloat16* __restrict__ Y, int ytile0)
{
  int bz = blockIdx.z, t = bz >> 4;
  gemm_core<4, 512, 1024, true, true>(
      Wpw + (size_t)t * C3 * Cch,
      xnT + (size_t)bz * HWp * Cch,
      t ? wm_pw_b : img_pw_b,
      Y + (size_t)bz * C3 * HWp,
      (blockIdx.y + ytile0) * 128);
}

__global__ __launch_bounds__(256) void k_proj_gemm(
    const __hip_bfloat16* __restrict__ projT, const __hip_bfloat16* __restrict__ attnT,
    float* __restrict__ out)
{
  int b = blockIdx.z;
  gemm_core<4, 1024, 1024, false, false>(
      projT, attnT + (size_t)b * HWp * 1024, nullptr, out + (size_t)b * Cch * HWp,
      blockIdx.y * 128);
}

// ---------------- 6. depthwise 3x3 grouped conv, LDS-staged, packed-f32 math ----------------
// VALU-bound kernel (r5 counters: VALUBusy 70%, MfmaUtil 0). v_pk_fma_f32 halves the
// FMA stream via SHIFTED ACCUMULATORS: aligned pairs acc2[j]=(out2j,out2j+1) take the
// center tap; misaligned pairs mpair[jj]=(out2jj-1,out2jj) take the +-1 taps -- every
// pk_fma consumes a naturally ALIGNED input pair (in2j,in2j+1) straight from unpack
// (no alignbit/repack). One scalar merge per output at the end.
//   tap0 (in[x]->out[x+1]): mpair[j+1] += vp[j]*wk0, j=-1..3
//   tap1 (center)         : acc2 [j]   += vp[j]*wk1, j= 0..3
//   tap2 (in[x]->out[x-1]): mpair[j]   += vp[j]*wk2, j= 0..4
//   out[2j] = acc2[j].x + mpair[j].y ; out[2j+1] = acc2[j].y + mpair[j+1].x
// Split into 2 dispatches (tb0 = 0,16) for profiler visibility.
__global__ __launch_bounds__(256) void k_dw(
    const __hip_bfloat16* __restrict__ Y,
    const float* __restrict__ img_dw_w, const float* __restrict__ img_dw_b,
    const float* __restrict__ wm_dw_w,  const float* __restrict__ wm_dw_b,
    __hip_bfloat16* __restrict__ QKV, int tb0)
{
  __shared__ __hip_bfloat16 sm[6 * 1024 + 8];   // +8 pad: edge dword reads stay in-bounds
  int blk = blockIdx.x;                         // 4096 = 16 tb x 256 gb
  int gb = blk & 255, tb = (blk >> 8) + tb0;
  int tid = threadIdx.x;
  const __hip_bfloat16* src = Y + ((size_t)tb * C3 + gb * 6) * HWp;  // 6 contiguous ch
#pragma unroll
  for (int s = 0; s < 3; s++) {
    int lin = tid + s * 256;                    // 768 x 16B = 12KB
    async16(sm + lin * 8, src + lin * 8);
  }
  __syncthreads();                              // vmcnt(0) drain before barrier

  int gl = __builtin_amdgcn_readfirstlane(tid >> 7);   // wave-uniform (2 waves per gl)
  int t  = tid & 127;
  int w0 = (t & 3) * 8;
  int h  = t >> 2;                              // 0..31
  int g  = gb * 2 + gl;
  int tsel = tb >> 4;
  const float* dww = (tsel ? wm_dw_w : img_dw_w) + g * 81;   // 3 o x 27
  const float* dwb = (tsel ? wm_dw_b : img_dw_b) + g * 3;
  f32x2 acc2[3][4];   // (out2j, out2j+1), bias pre-added
  f32x2 mpair[3][5];  // (out2jj-1, out2jj)
#pragma unroll
  for (int o = 0; o < 3; o++) {
    float bv = dwb[o];
#pragma unroll
    for (int j = 0; j < 4; j++) { acc2[o][j][0] = bv; acc2[o][j][1] = bv; }
#pragma unroll
    for (int j = 0; j < 5; j++) { mpair[o][j][0] = 0.f; mpair[o][j][1] = 0.f; }
  }
  const bool mlo = (w0 == 0), mhi = (w0 == 24);
#pragma unroll
  for (int i = 0; i < 3; i++) {
#pragma unroll
    for (int kh = 0; kh < 3; kh++) {
      int hh = h + kh - 1;
      if ((unsigned)hh > 31u) continue;
      const __hip_bfloat16* row = sm + (gl * 3 + i) * 1024 + hh * 32;
      bf16x8 c0 = *(const bf16x8*)(row + w0);        // halfs [w0, w0+8), 16B-aligned
      unsigned um1 = 0u, u4 = 0u;
      if (!mlo) um1 = *(const unsigned*)(row + w0 - 2);   // halfs w0-2, w0-1
      if (!mhi) u4  = *(const unsigned*)(row + w0 + 8);   // halfs w0+8, w0+9
      const unsigned* cu = (const unsigned*)&c0;
      f32x2 vp[6];                                   // vp[k] = input pair j = k-1
      vp[0] = up2(um1);
#pragma unroll
      for (int j = 0; j < 4; j++) vp[1 + j] = up2(cu[j]);
      vp[5] = up2(u4);
#pragma unroll
      for (int o = 0; o < 3; o++) {
        float wk0 = dww[o*27 + i*9 + kh*3 + 0];
        float wk1 = dww[o*27 + i*9 + kh*3 + 1];
        float wk2 = dww[o*27 + i*9 + kh*3 + 2];
        f32x2 k0; k0[0] = wk0; k0[1] = wk0;
        f32x2 k1; k1[0] = wk1; k1[1] = wk1;
        f32x2 k2; k2[0] = wk2; k2[1] = wk2;
#pragma unroll
        for (int j = 0; j < 4; j++) PKFMA(acc2[o][j], vp[j + 1], k1);
#pragma unroll
        for (int jj = 0; jj < 5; jj++) PKFMA(mpair[o][jj], vp[jj], k0);
#pragma unroll
        for (int jj = 0; jj < 5; jj++) PKFMA(mpair[o][jj], vp[jj + 1], k2);
      }
    }
  }
#pragma unroll
  for (int o = 0; o < 3; o++) {
    union { unsigned short us[8]; uint4 v4; } pk;
#pragma unroll
    for (int j = 0; j < 4; j++) {
      pk.us[2*j]     = f2bf(acc2[o][j][0] + mpair[o][j][1]);
      pk.us[2*j + 1] = f2bf(acc2[o][j][1] + mpair[o][j + 1][0]);
    }
    *(uint4*)(QKV + ((size_t)tb * C3 + g * 3 + o) * HWp + h * 32 + w0) = pk.v4;
  }
}

// ---------------- 7. attention scores + softmax over q ----------------
__global__ __launch_bounds__(256) void k_attn_scores(
    const __hip_bfloat16* __restrict__ QKV, __hip_bfloat16* __restrict__ ATg)
{
  int blk = blockIdx.x, kh = blk & 1, m = (blk >> 1) & 1, bn = blk >> 2;
  int b = bn >> 3, nh = bn & 7;
  int tid = threadIdx.x, lane = tid & 63, wv = tid >> 6;
  int lr = lane & 15, lq = lane >> 4;
  const __hip_bfloat16* kb =
      QKV + (((size_t)(kh * 16 + b)) * C3 + 512 + nh * 64 + (wv * 16 + lr)) * HWp + lq * 8;
  const __hip_bfloat16* qbase[4];
#pragma unroll
  for (int qt = 0; qt < 4; qt++)
    qbase[qt] = QKV + (((size_t)(m * 16 + b)) * C3 + nh * 64 + qt * 16 + lr) * HWp + lq * 8;

  f32x4 acc[4] = {};
  for (int p0 = 0; p0 < HWp; p0 += 32) {
    bf16x8 bk = *(const bf16x8*)(kb + p0);
#pragma unroll
    for (int qt = 0; qt < 4; qt++) {
      bf16x8 aq = *(const bf16x8*)(qbase[qt] + p0);
      acc[qt] = __builtin_amdgcn_mfma_f32_16x16x32_bf16(aq, bk, acc[qt], 0, 0, 0);
    }
  }
  __shared__ float S[64][65];
  __shared__ float redmax[4][64];
  __shared__ float redsum[4][64];
  __shared__ __hip_bfloat16 Ash[64][72];
#pragma unroll
  for (int qt = 0; qt < 4; qt++)
#pragma unroll
    for (int r = 0; r < 4; r++)
      S[qt * 16 + lq * 4 + r][wv * 16 + lr] = acc[qt][r];
  __syncthreads();
  int k = tid & 63, sub = tid >> 6;
  float vals[16], mx = -1e30f;
#pragma unroll
  for (int j = 0; j < 16; j++) { vals[j] = S[sub * 16 + j][k]; mx = fmaxf(mx, vals[j]); }
  redmax[sub][k] = mx;
  __syncthreads();
  float M = fmaxf(fmaxf(redmax[0][k], redmax[1][k]), fmaxf(redmax[2][k], redmax[3][k]));
  float ssum = 0.f;
#pragma unroll
  for (int j = 0; j < 16; j++) { vals[j] = __expf(vals[j] - M); ssum += vals[j]; }
  redsum[sub][k] = ssum;
  __syncthreads();
  float inv = 1.f / (redsum[0][k] + redsum[1][k] + redsum[2][k] + redsum[3][k]);
#pragma unroll
  for (int j = 0; j < 16; j++) Ash[sub * 16 + j][k] = __float2bfloat16(vals[j] * inv);
  __syncthreads();
  __hip_bfloat16* outp = ATg + ((size_t)(bn * 2 + m)) * 64 * 128 + kh * 64;
#pragma unroll
  for (int s = 0; s < 2; s++) {
    int id = tid + s * 256, row = id >> 3, seg = (id & 7) * 8;
    *(uint4*)&outp[(size_t)row * 128 + seg] = *(const uint4*)&Ash[row][seg];
  }
}

// ---------------- 8. attention output ----------------
__global__ __launch_bounds__(256) void k_attn_out(
    const __hip_bfloat16* __restrict__ QKV, const __hip_bfloat16* __restrict__ ATg,
    __hip_bfloat16* __restrict__ attnT)
{
  int blk = blockIdx.x, pc = blk & 3, bn = blk >> 2, b = bn >> 3, nh = bn & 7;
  int tid = threadIdx.x, lane = tid & 63, wv = tid >> 6;
  int lr = lane & 15, lq = lane >> 4;
  __shared__ __hip_bfloat16 ATs[2][64][136];
  __shared__ __hip_bfloat16 VTs[64][136];
#pragma unroll
  for (int m = 0; m < 2; m++) {
    const __hip_bfloat16* src = ATg + ((size_t)(bn * 2 + m)) * 64 * 128;
#pragma unroll
    for (int s = 0; s < 4; s++) {
      int id = tid + s * 256, row = id >> 4, seg = (id & 15) * 8;
      *(uint4*)&ATs[m][row][seg] = *(const uint4*)&src[row * 128 + seg];
    }
  }
  const int vk0 = (tid >> 3) * 4, vps = (tid & 7) * 8;
  for (int ps = 0; ps < 4; ps++) {
    int p0 = pc * 256 + ps * 64;
    __syncthreads();
    union { uint4 v4; unsigned short us[8]; } ld[4];
#pragma unroll
    for (int j = 0; j < 4; j++) {
      int kk = vk0 + j, tk = kk >> 6, hc = kk & 63;
      ld[j].v4 = *(const uint4*)(QKV +
          (((size_t)(tk * 16 + b)) * C3 + 1024 + nh * 64 + hc) * HWp + p0 + vps);
    }
#pragma unroll
    for (int e = 0; e < 8; e++) {
      uint2 w;
      w.x = (unsigned)ld[0].us[e] | ((unsigned)ld[1].us[e] << 16);
      w.y = (unsigned)ld[2].us[e] | ((unsigned)ld[3].us[e] << 16);
      *(uint2*)&VTs[vps + e][vk0] = w;
    }
    __syncthreads();
#pragma unroll
    for (int m = 0; m < 2; m++) {
      f32x4 oacc[4] = {};
#pragma unroll
      for (int ks = 0; ks < 4; ks++) {
        bf16x8 bv = *(const bf16x8*)&VTs[wv * 16 + lr][ks * 32 + lq * 8];
#pragma unroll
        for (int qt = 0; qt < 4; qt++) {
          bf16x8 av = *(const bf16x8*)&ATs[m][qt * 16 + lr][ks * 32 + lq * 8];
          oacc[qt] = __builtin_amdgcn_mfma_f32_16x16x32_bf16(av, bv, oacc[qt], 0, 0, 0);
        }
      }
#pragma unroll
      for (int qt = 0; qt < 4; qt++) {
        int q = qt * 16 + lq * 4;
        int d = nh * 128 + m * 64 + q;
        int p = p0 + wv * 16 + lr;
        union { unsigned short us[4]; uint2 v2; } pk;
#pragma unroll
        for (int r = 0; r < 4; r++) pk.us[r] = f2bf(oacc[qt][r]);
        *(uint2*)&attnT[((size_t)b * HWp + p) * 1024 + d] = pk.v2;
      }
    }
  }
}

extern "C" void kernel_launch(void* const* d_in, const int* in_sizes, int n_in,
                              void* d_out, int out_size, void* d_ws, size_t ws_size,
                              hipStream_t stream)
{
  (void)in_sizes; (void)n_in; (void)out_size; (void)ws_size;
  const float* image     = (const float*)d_in[0];
  const float* watermark = (const float*)d_in[1];
  const float* img_ln_w  = (const float*)d_in[2];
  const float* img_ln_b  = (const float*)d_in[3];
  const float* wm_ln_w   = (const float*)d_in[4];
  const float* wm_ln_b   = (const float*)d_in[5];
  const float* img_pw_w  = (const float*)d_in[6];
  const float* img_pw_b  = (const float*)d_in[7];
  const float* img_dw_w  = (const float*)d_in[8];
  const float* img_dw_b  = (const float*)d_in[9];
  const float* wm_pw_w   = (const float*)d_in[10];
  const float* wm_pw_b   = (const float*)d_in[11];
  const float* wm_dw_w   = (const float*)d_in[12];
  const float* wm_dw_b   = (const float*)d_in[13];
  const float* proj      = (const float*)d_in[14];

  char* ws = (char*)d_ws;
  // workspace map (high-water ~232 MiB); aliases are lifetime-disjoint:
  //   attnT aliases xnT (xnT dead after k_pw_gemm); ATg aliases Y (Y dead after k_dw)
  __hip_bfloat16* Wpw    = (__hip_bfloat16*)(ws + 0);            // 3.0 MiB
  __hip_bfloat16* projT  = (__hip_bfloat16*)(ws + 3145728);      // 1.0 MiB
  float*          lnpart = (float*)(ws + 4194304);               // 16 KiB
  __hip_bfloat16* xnT    = (__hip_bfloat16*)(ws + 5242880);      // 32 MiB
  __hip_bfloat16* attnT  = xnT;                                  // alias
  __hip_bfloat16* Y      = (__hip_bfloat16*)(ws + 41943040);     // 96 MiB
  __hip_bfloat16* ATg    = Y;                                    // alias (4 MiB)
  __hip_bfloat16* QKV    = (__hip_bfloat16*)(ws + 142606336);    // 96 MiB

  k_prep_ln<<<5632, 256, 0, stream>>>(img_pw_w, wm_pw_w, proj, image, watermark,
                                      Wpw, projT, lnpart);
  k_norm_t<<<8192, 256, 0, stream>>>(image, watermark, img_ln_w, img_ln_b,
                                     wm_ln_w, wm_ln_b, lnpart, xnT);
  dim3 gpw(8, 6, 32);
  k_pw_gemm<<<gpw, 256, 0, stream>>>(Wpw, xnT, img_pw_b, wm_pw_b, Y, 0);
  k_pw_gemm<<<gpw, 256, 0, stream>>>(Wpw, xnT, img_pw_b, wm_pw_b, Y, 6);
  k_dw<<<4096, 256, 0, stream>>>(Y, img_dw_w, img_dw_b, wm_dw_w, wm_dw_b, QKV, 0);
  k_dw<<<4096, 256, 0, stream>>>(Y, img_dw_w, img_dw_b, wm_dw_w, wm_dw_b, QKV, 16);
  k_attn_scores<<<512, 256, 0, stream>>>(QKV, ATg);
  k_attn_out<<<512, 256, 0, stream>>>(QKV, ATg, attnT);
  dim3 gpj(8, 4, 16);
  k_proj_gemm<<<gpj, 256, 0, stream>>>(projT, attnT, (float*)d_out);
}

// Round 7
// 375.535 us; speedup vs baseline: 1.0135x; 1.0135x over previous
//
#include <hip/hip_runtime.h>
#include <hip/hip_bf16.h>
#include <stdint.h>

// Problem dims: B=16, C=512, H=W=32, NH=8, HC=64, HW=1024, 3C=1536
#define Bn  16
#define Cch 512
#define C3  1536
#define HWp 1024

typedef __attribute__((ext_vector_type(8))) short bf16x8;    // 8 bf16 = 4 VGPRs (MFMA A/B frag)
typedef __attribute__((ext_vector_type(4))) float f32x4;     // 16x16 MFMA C/D frag

#define DEV static __device__ __forceinline__

DEV float bflo(unsigned u) { return __builtin_bit_cast(float, u << 16); }
DEV float bfhi(unsigned u) { return __builtin_bit_cast(float, u & 0xffff0000u); }
DEV float bf1(unsigned short us) { return __builtin_bit_cast(float, (unsigned)us << 16); }
DEV unsigned short f2bf(float f) {
  __hip_bfloat16 h = __float2bfloat16(f);
  return __builtin_bit_cast(unsigned short, h);
}

// async global->LDS, 16B per lane. LDS dest must be wave-uniform base + lane*16.
DEV void async16(__hip_bfloat16* lds, const __hip_bfloat16* g) {
  __builtin_amdgcn_global_load_lds(
      (const __attribute__((address_space(1))) unsigned*)g,
      (__attribute__((address_space(3))) unsigned*)lds, 16, 0, 0);
}

// ---------------- 1. weight prep (fp32->bf16, vectorized) + LayerNorm partial sums ----------------
// blocks [0,1536): pw-weight cast as float4->bf16x4 (393216 float4)
// blocks [1536,3584): proj transpose (scalar reads, coalesced writes)
// blocks [3584,5632): ln partial (2048 = t*1024 + b*64 + chunk)
__global__ __launch_bounds__(256) void k_prep_ln(
    const float* __restrict__ img_pw_w, const float* __restrict__ wm_pw_w,
    const float* __restrict__ proj,
    const float* __restrict__ image, const float* __restrict__ watermark,
    __hip_bfloat16* __restrict__ Wpw, __hip_bfloat16* __restrict__ projT,
    float* __restrict__ part)
{
  __shared__ float ls[4], lss[4];
  int blkid = blockIdx.x;
  if (blkid < 1536) {
    int i = blkid * 256 + threadIdx.x;      // float4 index, 0..393215
    const int NW4 = (C3 * Cch) / 4;         // 196608
    const float4* srcv = (i < NW4) ? (const float4*)img_pw_w : (const float4*)wm_pw_w;
    int j = (i < NW4) ? i : i - NW4;
    float4 v = srcv[j];
    ushort4 o = { f2bf(v.x), f2bf(v.y), f2bf(v.z), f2bf(v.w) };
    ((ushort4*)Wpw)[i] = o;
    return;
  }
  if (blkid < 3584) {
    int j = (blkid - 1536) * 256 + threadIdx.x;   // 0..524287
    int c = j >> 10, d = j & 1023;
    projT[(size_t)c * 1024 + d] = __float2bfloat16(proj[(size_t)d * 512 + c]);
    return;
  }
  int blk = blkid - 3584;
  int chunk = blk & 63, b = (blk >> 6) & 15, t = blk >> 10;
  const float* x = (t ? watermark : image) + (size_t)b * Cch * HWp + chunk * 8192;
  const float4* xv = (const float4*)x;
  float s = 0.f, ss = 0.f;
#pragma unroll
  for (int i = 0; i < 8; i++) {
    float4 v = xv[threadIdx.x + i * 256];
    s  += v.x + v.y + v.z + v.w;
    ss += v.x * v.x + v.y * v.y + v.z * v.z + v.w * v.w;
  }
#pragma unroll
  for (int off = 32; off; off >>= 1) { s += __shfl_down(s, off); ss += __shfl_down(ss, off); }
  int wv = threadIdx.x >> 6;
  if ((threadIdx.x & 63) == 0) { ls[wv] = s; lss[wv] = ss; }
  __syncthreads();
  if (threadIdx.x == 0) {
    part[blk * 2]     = ls[0] + ls[1] + ls[2] + ls[3];
    part[blk * 2 + 1] = lss[0] + lss[1] + lss[2] + lss[3];
  }
}

// ---------------- 4. normalize + affine + transpose -> xnT[t][b][p][c] bf16 ----------------
// (ln finalize folded in: wave 0 reduces this (t,b)'s 64 partial pairs)
__global__ __launch_bounds__(256) void k_norm_t(
    const float* __restrict__ image, const float* __restrict__ watermark,
    const float* __restrict__ img_w, const float* __restrict__ img_b,
    const float* __restrict__ wm_w,  const float* __restrict__ wm_b,
    const float* __restrict__ part, __hip_bfloat16* __restrict__ xnT)
{
  int blk = blockIdx.x;
  int ct = blk & 15, pt = (blk >> 4) & 15, b = (blk >> 8) & 15, t = blk >> 12;
  int c0 = ct * 32, p0 = pt * 64;
  const float* x   = (t ? watermark : image) + (size_t)b * Cch * HWp;
  const float* wgt = t ? wm_w : img_w;
  const float* bia = t ? wm_b : img_b;
  int tid = threadIdx.x;
  __shared__ float sst[2];
  if (tid < 64) {
    float S  = part[(t * 1024 + b * 64 + tid) * 2];
    float SS = part[(t * 1024 + b * 64 + tid) * 2 + 1];
#pragma unroll
    for (int off = 32; off; off >>= 1) { S += __shfl_down(S, off); SS += __shfl_down(SS, off); }
    if (tid == 0) {
      const float inv = 1.f / (float)(Cch * HWp);
      float mu  = S * inv;
      float var = SS * inv - mu * mu;
      sst[0] = mu;
      sst[1] = rsqrtf(var + 1e-5f);
    }
  }
  __syncthreads();
  float mu = sst[0], rstd = sst[1];
  __shared__ float tile[32 * 66];
  {
    int c = tid >> 3, s = tid & 7;
    const float* xr = x   + (size_t)(c0 + c) * HWp + p0;
    const float* wr = wgt + (size_t)(c0 + c) * HWp + p0;
    const float* br = bia + (size_t)(c0 + c) * HWp + p0;
#pragma unroll
    for (int j = 0; j < 2; j++) {
      int f = s + j * 8;                 // float4 slot 0..15
      float4 xv = *(const float4*)&xr[f * 4];
      float4 wv = *(const float4*)&wr[f * 4];
      float4 bv = *(const float4*)&br[f * 4];
      float n0 = (xv.x - mu) * rstd * wv.x + bv.x;
      float n1 = (xv.y - mu) * rstd * wv.y + bv.y;
      float n2 = (xv.z - mu) * rstd * wv.z + bv.z;
      float n3 = (xv.w - mu) * rstd * wv.w + bv.w;
      *(float2*)&tile[c * 66 + f * 4]     = make_float2(n0, n1);
      *(float2*)&tile[c * 66 + f * 4 + 2] = make_float2(n2, n3);
    }
  }
  __syncthreads();
  {
    int p = tid >> 2, cq = tid & 3;      // 64 p x 4 c-groups of 8
    union { unsigned short us[8]; uint4 v4; } pk;
#pragma unroll
    for (int j = 0; j < 8; j++) pk.us[j] = f2bf(tile[(cq * 8 + j) * 66 + p]);
    __hip_bfloat16* dst = xnT + ((size_t)(t * 16 + b)) * HWp * Cch
                        + (size_t)(p0 + p) * Cch + c0 + cq * 8;
    *(uint4*)dst = pk.v4;
  }
}

// ---------------- 5. bf16 BT-GEMM core: 16x16x32 MFMA + XOR-swizzled LDS ----------------
template<int MI, int Kdim, int Ncols, bool OBF, bool HB>
DEV void gemm_core(const __hip_bfloat16* __restrict__ A,
                   const __hip_bfloat16* __restrict__ Bt,
                   const float* __restrict__ bias, void* __restrict__ Cout, int m0)
{
  constexpr int MT = MI * 32;
  __shared__ __hip_bfloat16 As[MT * 64];
  __shared__ __hip_bfloat16 Bs[128 * 64];
  const int tid = threadIdx.x, lane = tid & 63, wv = tid >> 6;
  const int lr = lane & 15, lq = lane >> 4;
  const int wm = (wv >> 1) * (MI * 16), wn = (wv & 1) * 64;
  const int n0 = blockIdx.x * 128;
  f32x4 acc[MI][4] = {};
  const int srow = tid >> 3, sslot = tid & 7;
  const int sseg = (sslot ^ (srow & 7)) * 8;    // swizzled global segment (halfs)
  for (int k0 = 0; k0 < Kdim; k0 += 64) {
#pragma unroll
    for (int c = 0; c < MI; c++) {
      int row = srow + c * 32;                  // row&7 == srow&7 (c*32 mult of 8)
      async16(&As[row * 64 + sslot * 8], &A[(size_t)(m0 + row) * Kdim + k0 + sseg]);
    }
#pragma unroll
    for (int c = 0; c < 4; c++) {
      int row = srow + c * 32;
      async16(&Bs[row * 64 + sslot * 8], &Bt[(size_t)(n0 + row) * Kdim + k0 + sseg]);
    }
    __syncthreads();   // compiler emits vmcnt(0) drain here
#pragma unroll
    for (int ks = 0; ks < 2; ks++) {
      bf16x8 af[MI], bfr[4];
#pragma unroll
      for (int mi = 0; mi < MI; mi++) {
        int r = wm + mi * 16 + lr;              // r&7 == lr&7
        af[mi]  = *(const bf16x8*)&As[r * 64 + (((ks * 4 + lq) ^ (lr & 7)) * 8)];
      }
#pragma unroll
      for (int ni = 0; ni < 4; ni++) {
        int r = wn + ni * 16 + lr;
        bfr[ni] = *(const bf16x8*)&Bs[r * 64 + (((ks * 4 + lq) ^ (lr & 7)) * 8)];
      }
#pragma unroll
      for (int mi = 0; mi < MI; mi++)
#pragma unroll
        for (int ni = 0; ni < 4; ni++)
          acc[mi][ni] = __builtin_amdgcn_mfma_f32_16x16x32_bf16(af[mi], bfr[ni], acc[mi][ni], 0, 0, 0);
    }
    __syncthreads();
  }
#pragma unroll
  for (int mi = 0; mi < MI; mi++) {
    int mrow = m0 + wm + mi * 16 + lq * 4;
#pragma unroll
    for (int ni = 0; ni < 4; ni++) {
      int ncol = n0 + wn + ni * 16 + lr;
#pragma unroll
      for (int r = 0; r < 4; r++) {
        float y = acc[mi][ni][r];
        int row = mrow + r;
        if (HB) y += bias[row];
        if (OBF) ((__hip_bfloat16*)Cout)[(size_t)row * Ncols + ncol] = __float2bfloat16(y);
        else     ((float*)Cout)[(size_t)row * Ncols + ncol] = y;
      }
    }
  }
}

__global__ __launch_bounds__(256) void k_pw_gemm(
    const __hip_bfloat16* __restrict__ Wpw, const __hip_bfloat16* __restrict__ xnT,
    const float* __restrict__ img_pw_b, const float* __restrict__ wm_pw_b,
    __hip_bfloat16* __restrict__ Y, int ytile0)
{
  int bz = blockIdx.z, t = bz >> 4;
  gemm_core<4, 512, 1024, true, true>(
      Wpw + (size_t)t * C3 * Cch,
      xnT + (size_t)bz * HWp * Cch,
      t ? wm_pw_b : img_pw_b,
      Y + (size_t)bz * C3 * HWp,
      (blockIdx.y + ytile0) * 128);
}

__global__ __launch_bounds__(256) void k_proj_gemm(
    const __hip_bfloat16* __restrict__ projT, const __hip_bfloat16* __restrict__ attnT,
    float* __restrict__ out)
{
  int b = blockIdx.z;
  gemm_core<4, 1024, 1024, false, false>(
      projT, attnT + (size_t)b * HWp * 1024, nullptr, out + (size_t)b * Cch * HWp,
      blockIdx.y * 128);
}

// ---------------- 6. depthwise 3x3 grouped conv, LDS-staged (verified scalar form) ----------------
// Split into 2 dispatches (tb0 = 0,16) for profiler visibility.
__global__ __launch_bounds__(256) void k_dw(
    const __hip_bfloat16* __restrict__ Y,
    const float* __restrict__ img_dw_w, const float* __restrict__ img_dw_b,
    const float* __restrict__ wm_dw_w,  const float* __restrict__ wm_dw_b,
    __hip_bfloat16* __restrict__ QKV, int tb0)
{
  __shared__ __hip_bfloat16 sm[6 * 1024];   // [glch][px], linear (async dest)
  int blk = blockIdx.x;                     // 4096 = 16 tb x 256 gb
  int gb = blk & 255, tb = (blk >> 8) + tb0;
  int tid = threadIdx.x;
  const __hip_bfloat16* src = Y + ((size_t)tb * C3 + gb * 6) * HWp;  // 6 contiguous ch
#pragma unroll
  for (int s = 0; s < 3; s++) {
    int lin = tid + s * 256;                // 768 x 16B = 12KB
    async16(sm + lin * 8, src + lin * 8);
  }
  __syncthreads();                          // vmcnt(0) drain before barrier

  int gl = __builtin_amdgcn_readfirstlane(tid >> 7);   // wave-uniform (2 waves per gl)
  int t  = tid & 127;
  int w0 = (t & 3) * 8;
  int h  = t >> 2;                          // 0..31
  int g  = gb * 2 + gl;
  int tsel = tb >> 4;
  const float* dww = (tsel ? wm_dw_w : img_dw_w) + g * 81;   // 3 o x 27
  const float* dwb = (tsel ? wm_dw_b : img_dw_b) + g * 3;
  float acc[3][8];
#pragma unroll
  for (int o = 0; o < 3; o++) {
    float bv = dwb[o];
#pragma unroll
    for (int w = 0; w < 8; w++) acc[o][w] = bv;
  }
  const bool mlo = (w0 == 0), mhi = (w0 == 24);
#pragma unroll
  for (int i = 0; i < 3; i++) {
#pragma unroll
    for (int kh = 0; kh < 3; kh++) {
      int hh = h + kh - 1;
      if ((unsigned)hh > 31u) continue;
      const __hip_bfloat16* row = sm + (gl * 3 + i) * 1024 + hh * 32;
      bf16x8 c0 = *(const bf16x8*)(row + w0);          // halfs [w0, w0+8), 16B-aligned
      float v[10];
      const unsigned* cu = (const unsigned*)&c0;
#pragma unroll
      for (int j = 0; j < 4; j++) { unsigned u = cu[j]; v[1 + 2*j] = bflo(u); v[2 + 2*j] = bfhi(u); }
      v[0] = mlo ? 0.f : bf1(*(const unsigned short*)(row + w0 - 1));   // half w0-1
      v[9] = mhi ? 0.f : bf1(*(const unsigned short*)(row + w0 + 8));   // half w0+8
#pragma unroll
      for (int o = 0; o < 3; o++) {
        float wk0 = dww[o*27 + i*9 + kh*3 + 0];
        float wk1 = dww[o*27 + i*9 + kh*3 + 1];
        float wk2 = dww[o*27 + i*9 + kh*3 + 2];
#pragma unroll
        for (int w = 0; w < 8; w++)
          acc[o][w] += v[w] * wk0 + v[w + 1] * wk1 + v[w + 2] * wk2;
      }
    }
  }
#pragma unroll
  for (int o = 0; o < 3; o++) {
    union { unsigned short us[8]; uint4 v4; } pk;
#pragma unroll
    for (int w = 0; w < 8; w++) pk.us[w] = f2bf(acc[o][w]);
    *(uint4*)(QKV + ((size_t)tb * C3 + g * 3 + o) * HWp + h * 32 + w0) = pk.v4;
  }
}

// ---------------- 7. attention scores + softmax over q ----------------
// r6 counters: 50 us, MfmaUtil 3%, VALUBusy 2%, HBM 18%, Occ 17% -> pure latency-bound
// (8 waves/CU, 32-iter serial load->MFMA chain). Fix: 512 thr = 8 waves =
// 4 K-quarters x 2 p-halves (16 iter each, unroll 2 -> 10 loads in flight);
// partial S per p-half into Sp[2], softmax reads the sum. 3 blocks/CU (46.5 KB LDS).
__global__ __launch_bounds__(512) void k_attn_scores(
    const __hip_bfloat16* __restrict__ QKV, __hip_bfloat16* __restrict__ ATg)
{
  int blk = blockIdx.x, kh = blk & 1, m = (blk >> 1) & 1, bn = blk >> 2;
  int b = bn >> 3, nh = bn & 7;
  int tid = threadIdx.x, lane = tid & 63, wv8 = tid >> 6;
  int wv = wv8 & 3, ph = wv8 >> 2;          // K-quarter, p-half
  int lr = lane & 15, lq = lane >> 4;
  const __hip_bfloat16* kb =
      QKV + (((size_t)(kh * 16 + b)) * C3 + 512 + nh * 64 + (wv * 16 + lr)) * HWp
          + ph * 512 + lq * 8;
  const __hip_bfloat16* qbase[4];
#pragma unroll
  for (int qt = 0; qt < 4; qt++)
    qbase[qt] = QKV + (((size_t)(m * 16 + b)) * C3 + nh * 64 + qt * 16 + lr) * HWp
              + ph * 512 + lq * 8;

  f32x4 acc[4] = {};
#pragma unroll 2
  for (int p0 = 0; p0 < 512; p0 += 32) {
    bf16x8 bk = *(const bf16x8*)(kb + p0);
#pragma unroll
    for (int qt = 0; qt < 4; qt++) {
      bf16x8 aq = *(const bf16x8*)(qbase[qt] + p0);
      acc[qt] = __builtin_amdgcn_mfma_f32_16x16x32_bf16(aq, bk, acc[qt], 0, 0, 0);
    }
  }
  __shared__ float Sp[2][64][65];           // [p-half][q][k]
  __shared__ float redmax[8][64];
  __shared__ float redsum[8][64];
  __shared__ __hip_bfloat16 Ash[64][72];
#pragma unroll
  for (int qt = 0; qt < 4; qt++)
#pragma unroll
    for (int r = 0; r < 4; r++)
      Sp[ph][qt * 16 + lq * 4 + r][wv * 16 + lr] = acc[qt][r];
  __syncthreads();
  int k = tid & 63, sub = tid >> 6;         // 8 subs x 8 q-rows
  float vals[8], mx = -1e30f;
#pragma unroll
  for (int j = 0; j < 8; j++) {
    int row = sub * 8 + j;
    vals[j] = Sp[0][row][k] + Sp[1][row][k];
    mx = fmaxf(mx, vals[j]);
  }
  redmax[sub][k] = mx;
  __syncthreads();
  float M = redmax[0][k];
#pragma unroll
  for (int s = 1; s < 8; s++) M = fmaxf(M, redmax[s][k]);
  float ssum = 0.f;
#pragma unroll
  for (int j = 0; j < 8; j++) { vals[j] = __expf(vals[j] - M); ssum += vals[j]; }
  redsum[sub][k] = ssum;
  __syncthreads();
  float tot = redsum[0][k];
#pragma unroll
  for (int s = 1; s < 8; s++) tot += redsum[s][k];
  float inv = 1.f / tot;
#pragma unroll
  for (int j = 0; j < 8; j++) Ash[sub * 8 + j][k] = __float2bfloat16(vals[j] * inv);
  __syncthreads();
  __hip_bfloat16* outp = ATg + ((size_t)(bn * 2 + m)) * 64 * 128 + kh * 64;
  {
    int row = tid >> 3, seg = (tid & 7) * 8;
    *(uint4*)&outp[(size_t)row * 128 + seg] = *(const uint4*)&Ash[row][seg];
  }
}

// ---------------- 8. attention output ----------------
__global__ __launch_bounds__(256) void k_attn_out(
    const __hip_bfloat16* __restrict__ QKV, const __hip_bfloat16* __restrict__ ATg,
    __hip_bfloat16* __restrict__ attnT)
{
  int blk = blockIdx.x, pc = blk & 3, bn = blk >> 2, b = bn >> 3, nh = bn & 7;
  int tid = threadIdx.x, lane = tid & 63, wv = tid >> 6;
  int lr = lane & 15, lq = lane >> 4;
  __shared__ __hip_bfloat16 ATs[2][64][136];
  __shared__ __hip_bfloat16 VTs[64][136];
#pragma unroll
  for (int m = 0; m < 2; m++) {
    const __hip_bfloat16* src = ATg + ((size_t)(bn * 2 + m)) * 64 * 128;
#pragma unroll
    for (int s = 0; s < 4; s++) {
      int id = tid + s * 256, row = id >> 4, seg = (id & 15) * 8;
      *(uint4*)&ATs[m][row][seg] = *(const uint4*)&src[row * 128 + seg];
    }
  }
  const int vk0 = (tid >> 3) * 4, vps = (tid & 7) * 8;
  for (int ps = 0; ps < 4; ps++) {
    int p0 = pc * 256 + ps * 64;
    __syncthreads();
    union { uint4 v4; unsigned short us[8]; } ld[4];
#pragma unroll
    for (int j = 0; j < 4; j++) {
      int kk = vk0 + j, tk = kk >> 6, hc = kk & 63;
      ld[j].v4 = *(const uint4*)(QKV +
          (((size_t)(tk * 16 + b)) * C3 + 1024 + nh * 64 + hc) * HWp + p0 + vps);
    }
#pragma unroll
    for (int e = 0; e < 8; e++) {
      uint2 w;
      w.x = (unsigned)ld[0].us[e] | ((unsigned)ld[1].us[e] << 16);
      w.y = (unsigned)ld[2].us[e] | ((unsigned)ld[3].us[e] << 16);
      *(uint2*)&VTs[vps + e][vk0] = w;
    }
    __syncthreads();
#pragma unroll
    for (int m = 0; m < 2; m++) {
      f32x4 oacc[4] = {};
#pragma unroll
      for (int ks = 0; ks < 4; ks++) {
        bf16x8 bv = *(const bf16x8*)&VTs[wv * 16 + lr][ks * 32 + lq * 8];
#pragma unroll
        for (int qt = 0; qt < 4; qt++) {
          bf16x8 av = *(const bf16x8*)&ATs[m][qt * 16 + lr][ks * 32 + lq * 8];
          oacc[qt] = __builtin_amdgcn_mfma_f32_16x16x32_bf16(av, bv, oacc[qt], 0, 0, 0);
        }
      }
#pragma unroll
      for (int qt = 0; qt < 4; qt++) {
        int q = qt * 16 + lq * 4;
        int d = nh * 128 + m * 64 + q;
        int p = p0 + wv * 16 + lr;
        union { unsigned short us[4]; uint2 v2; } pk;
#pragma unroll
        for (int r = 0; r < 4; r++) pk.us[r] = f2bf(oacc[qt][r]);
        *(uint2*)&attnT[((size_t)b * HWp + p) * 1024 + d] = pk.v2;
      }
    }
  }
}

extern "C" void kernel_launch(void* const* d_in, const int* in_sizes, int n_in,
                              void* d_out, int out_size, void* d_ws, size_t ws_size,
                              hipStream_t stream)
{
  (void)in_sizes; (void)n_in; (void)out_size; (void)ws_size;
  const float* image     = (const float*)d_in[0];
  const float* watermark = (const float*)d_in[1];
  const float* img_ln_w  = (const float*)d_in[2];
  const float* img_ln_b  = (const float*)d_in[3];
  const float* wm_ln_w   = (const float*)d_in[4];
  const float* wm_ln_b   = (const float*)d_in[5];
  const float* img_pw_w  = (const float*)d_in[6];
  const float* img_pw_b  = (const float*)d_in[7];
  const float* img_dw_w  = (const float*)d_in[8];
  const float* img_dw_b  = (const float*)d_in[9];
  const float* wm_pw_w   = (const float*)d_in[10];
  const float* wm_pw_b   = (const float*)d_in[11];
  const float* wm_dw_w   = (const float*)d_in[12];
  const float* wm_dw_b   = (const float*)d_in[13];
  const float* proj      = (const float*)d_in[14];

  char* ws = (char*)d_ws;
  // workspace map (high-water ~232 MiB); aliases are lifetime-disjoint:
  //   attnT aliases xnT (xnT dead after k_pw_gemm); ATg aliases Y (Y dead after k_dw)
  __hip_bfloat16* Wpw    = (__hip_bfloat16*)(ws + 0);            // 3.0 MiB
  __hip_bfloat16* projT  = (__hip_bfloat16*)(ws + 3145728);      // 1.0 MiB
  float*          lnpart = (float*)(ws + 4194304);               // 16 KiB
  __hip_bfloat16* xnT    = (__hip_bfloat16*)(ws + 5242880);      // 32 MiB
  __hip_bfloat16* attnT  = xnT;                                  // alias
  __hip_bfloat16* Y      = (__hip_bfloat16*)(ws + 41943040);     // 96 MiB
  __hip_bfloat16* ATg    = Y;                                    // alias (4 MiB)
  __hip_bfloat16* QKV    = (__hip_bfloat16*)(ws + 142606336);    // 96 MiB

  k_prep_ln<<<5632, 256, 0, stream>>>(img_pw_w, wm_pw_w, proj, image, watermark,
                                      Wpw, projT, lnpart);
  k_norm_t<<<8192, 256, 0, stream>>>(image, watermark, img_ln_w, img_ln_b,
                                     wm_ln_w, wm_ln_b, lnpart, xnT);
  dim3 gpw(8, 6, 32);
  k_pw_gemm<<<gpw, 256, 0, stream>>>(Wpw, xnT, img_pw_b, wm_pw_b, Y, 0);
  k_pw_gemm<<<gpw, 256, 0, stream>>>(Wpw, xnT, img_pw_b, wm_pw_b, Y, 6);
  k_dw<<<4096, 256, 0, stream>>>(Y, img_dw_w, img_dw_b, wm_dw_w, wm_dw_b, QKV, 0);
  k_dw<<<4096, 256, 0, stream>>>(Y, img_dw_w, img_dw_b, wm_dw_w, wm_dw_b, QKV, 16);
  k_attn_scores<<<512, 512, 0, stream>>>(QKV, ATg);
  k_attn_out<<<512, 256, 0, stream>>>(QKV, ATg, attnT);
  dim3 gpj(8, 4, 16);
  k_proj_gemm<<<gpj, 256, 0, stream>>>(projT, attnT, (float*)d_out);
}

// Round 8
// 372.202 us; speedup vs baseline: 1.0225x; 1.0090x over previous
//
#include <hip/hip_runtime.h>
#include <hip/hip_bf16.h>
#include <stdint.h>

// Problem dims: B=16, C=512, H=W=32, NH=8, HC=64, HW=1024, 3C=1536
#define Bn  16
#define Cch 512
#define C3  1536
#define HWp 1024

typedef __attribute__((ext_vector_type(8))) short bf16x8;    // 8 bf16 = 4 VGPRs (MFMA A/B frag)
typedef __attribute__((ext_vector_type(4))) float f32x4;     // 16x16 MFMA C/D frag

#define DEV static __device__ __forceinline__

DEV float bflo(unsigned u) { return __builtin_bit_cast(float, u << 16); }
DEV float bfhi(unsigned u) { return __builtin_bit_cast(float, u & 0xffff0000u); }
DEV float bf1(unsigned short us) { return __builtin_bit_cast(float, (unsigned)us << 16); }
DEV unsigned short f2bf(float f) {
  __hip_bfloat16 h = __float2bfloat16(f);
  return __builtin_bit_cast(unsigned short, h);
}

// async global->LDS, 16B per lane. LDS dest must be wave-uniform base + lane*16.
DEV void async16(__hip_bfloat16* lds, const __hip_bfloat16* g) {
  __builtin_amdgcn_global_load_lds(
      (const __attribute__((address_space(1))) unsigned*)g,
      (__attribute__((address_space(3))) unsigned*)lds, 16, 0, 0);
}

// ---------------- 1. weight prep (fp32->bf16, vectorized) + LayerNorm partial sums ----------------
// blocks [0,1536): pw-weight cast as float4->bf16x4 (393216 float4)
// blocks [1536,3584): proj transpose (scalar reads, coalesced writes)
// blocks [3584,5632): ln partial (2048 = t*1024 + b*64 + chunk)
__global__ __launch_bounds__(256) void k_prep_ln(
    const float* __restrict__ img_pw_w, const float* __restrict__ wm_pw_w,
    const float* __restrict__ proj,
    const float* __restrict__ image, const float* __restrict__ watermark,
    __hip_bfloat16* __restrict__ Wpw, __hip_bfloat16* __restrict__ projT,
    float* __restrict__ part)
{
  __shared__ float ls[4], lss[4];
  int blkid = blockIdx.x;
  if (blkid < 1536) {
    int i = blkid * 256 + threadIdx.x;      // float4 index, 0..393215
    const int NW4 = (C3 * Cch) / 4;         // 196608
    const float4* srcv = (i < NW4) ? (const float4*)img_pw_w : (const float4*)wm_pw_w;
    int j = (i < NW4) ? i : i - NW4;
    float4 v = srcv[j];
    ushort4 o = { f2bf(v.x), f2bf(v.y), f2bf(v.z), f2bf(v.w) };
    ((ushort4*)Wpw)[i] = o;
    return;
  }
  if (blkid < 3584) {
    int j = (blkid - 1536) * 256 + threadIdx.x;   // 0..524287
    int c = j >> 10, d = j & 1023;
    projT[(size_t)c * 1024 + d] = __float2bfloat16(proj[(size_t)d * 512 + c]);
    return;
  }
  int blk = blkid - 3584;
  int chunk = blk & 63, b = (blk >> 6) & 15, t = blk >> 10;
  const float* x = (t ? watermark : image) + (size_t)b * Cch * HWp + chunk * 8192;
  const float4* xv = (const float4*)x;
  float s = 0.f, ss = 0.f;
#pragma unroll
  for (int i = 0; i < 8; i++) {
    float4 v = xv[threadIdx.x + i * 256];
    s  += v.x + v.y + v.z + v.w;
    ss += v.x * v.x + v.y * v.y + v.z * v.z + v.w * v.w;
  }
#pragma unroll
  for (int off = 32; off; off >>= 1) { s += __shfl_down(s, off); ss += __shfl_down(ss, off); }
  int wv = threadIdx.x >> 6;
  if ((threadIdx.x & 63) == 0) { ls[wv] = s; lss[wv] = ss; }
  __syncthreads();
  if (threadIdx.x == 0) {
    part[blk * 2]     = ls[0] + ls[1] + ls[2] + ls[3];
    part[blk * 2 + 1] = lss[0] + lss[1] + lss[2] + lss[3];
  }
}

// ---------------- 4. normalize + affine + transpose -> xnT[t][b][p][c] bf16 ----------------
// (ln finalize folded in: wave 0 reduces this (t,b)'s 64 partial pairs)
__global__ __launch_bounds__(256) void k_norm_t(
    const float* __restrict__ image, const float* __restrict__ watermark,
    const float* __restrict__ img_w, const float* __restrict__ img_b,
    const float* __restrict__ wm_w,  const float* __restrict__ wm_b,
    const float* __restrict__ part, __hip_bfloat16* __restrict__ xnT)
{
  int blk = blockIdx.x;
  int ct = blk & 15, pt = (blk >> 4) & 15, b = (blk >> 8) & 15, t = blk >> 12;
  int c0 = ct * 32, p0 = pt * 64;
  const float* x   = (t ? watermark : image) + (size_t)b * Cch * HWp;
  const float* wgt = t ? wm_w : img_w;
  const float* bia = t ? wm_b : img_b;
  int tid = threadIdx.x;
  __shared__ float sst[2];
  if (tid < 64) {
    float S  = part[(t * 1024 + b * 64 + tid) * 2];
    float SS = part[(t * 1024 + b * 64 + tid) * 2 + 1];
#pragma unroll
    for (int off = 32; off; off >>= 1) { S += __shfl_down(S, off); SS += __shfl_down(SS, off); }
    if (tid == 0) {
      const float inv = 1.f / (float)(Cch * HWp);
      float mu  = S * inv;
      float var = SS * inv - mu * mu;
      sst[0] = mu;
      sst[1] = rsqrtf(var + 1e-5f);
    }
  }
  __syncthreads();
  float mu = sst[0], rstd = sst[1];
  __shared__ float tile[32 * 66];
  {
    int c = tid >> 3, s = tid & 7;
    const float* xr = x   + (size_t)(c0 + c) * HWp + p0;
    const float* wr = wgt + (size_t)(c0 + c) * HWp + p0;
    const float* br = bia + (size_t)(c0 + c) * HWp + p0;
#pragma unroll
    for (int j = 0; j < 2; j++) {
      int f = s + j * 8;                 // float4 slot 0..15
      float4 xv = *(const float4*)&xr[f * 4];
      float4 wv = *(const float4*)&wr[f * 4];
      float4 bv = *(const float4*)&br[f * 4];
      float n0 = (xv.x - mu) * rstd * wv.x + bv.x;
      float n1 = (xv.y - mu) * rstd * wv.y + bv.y;
      float n2 = (xv.z - mu) * rstd * wv.z + bv.z;
      float n3 = (xv.w - mu) * rstd * wv.w + bv.w;
      *(float2*)&tile[c * 66 + f * 4]     = make_float2(n0, n1);
      *(float2*)&tile[c * 66 + f * 4 + 2] = make_float2(n2, n3);
    }
  }
  __syncthreads();
  {
    int p = tid >> 2, cq = tid & 3;      // 64 p x 4 c-groups of 8
    union { unsigned short us[8]; uint4 v4; } pk;
#pragma unroll
    for (int j = 0; j < 8; j++) pk.us[j] = f2bf(tile[(cq * 8 + j) * 66 + p]);
    __hip_bfloat16* dst = xnT + ((size_t)(t * 16 + b)) * HWp * Cch
                        + (size_t)(p0 + p) * Cch + c0 + cq * 8;
    *(uint4*)dst = pk.v4;
  }
}

// ---------------- 5. bf16 BT-GEMM core: 16x16x32 MFMA + XOR-swizzled LDS ----------------
template<int MI, int Kdim, int Ncols, bool OBF, bool HB>
DEV void gemm_core(const __hip_bfloat16* __restrict__ A,
                   const __hip_bfloat16* __restrict__ Bt,
                   const float* __restrict__ bias, void* __restrict__ Cout, int m0)
{
  constexpr int MT = MI * 32;
  __shared__ __hip_bfloat16 As[MT * 64];
  __shared__ __hip_bfloat16 Bs[128 * 64];
  const int tid = threadIdx.x, lane = tid & 63, wv = tid >> 6;
  const int lr = lane & 15, lq = lane >> 4;
  const int wm = (wv >> 1) * (MI * 16), wn = (wv & 1) * 64;
  const int n0 = blockIdx.x * 128;
  f32x4 acc[MI][4] = {};
  const int srow = tid >> 3, sslot = tid & 7;
  const int sseg = (sslot ^ (srow & 7)) * 8;    // swizzled global segment (halfs)
  for (int k0 = 0; k0 < Kdim; k0 += 64) {
#pragma unroll
    for (int c = 0; c < MI; c++) {
      int row = srow + c * 32;                  // row&7 == srow&7 (c*32 mult of 8)
      async16(&As[row * 64 + sslot * 8], &A[(size_t)(m0 + row) * Kdim + k0 + sseg]);
    }
#pragma unroll
    for (int c = 0; c < 4; c++) {
      int row = srow + c * 32;
      async16(&Bs[row * 64 + sslot * 8], &Bt[(size_t)(n0 + row) * Kdim + k0 + sseg]);
    }
    __syncthreads();   // compiler emits vmcnt(0) drain here
#pragma unroll
    for (int ks = 0; ks < 2; ks++) {
      bf16x8 af[MI], bfr[4];
#pragma unroll
      for (int mi = 0; mi < MI; mi++) {
        int r = wm + mi * 16 + lr;              // r&7 == lr&7
        af[mi]  = *(const bf16x8*)&As[r * 64 + (((ks * 4 + lq) ^ (lr & 7)) * 8)];
      }
#pragma unroll
      for (int ni = 0; ni < 4; ni++) {
        int r = wn + ni * 16 + lr;
        bfr[ni] = *(const bf16x8*)&Bs[r * 64 + (((ks * 4 + lq) ^ (lr & 7)) * 8)];
      }
#pragma unroll
      for (int mi = 0; mi < MI; mi++)
#pragma unroll
        for (int ni = 0; ni < 4; ni++)
          acc[mi][ni] = __builtin_amdgcn_mfma_f32_16x16x32_bf16(af[mi], bfr[ni], acc[mi][ni], 0, 0, 0);
    }
    __syncthreads();
  }
#pragma unroll
  for (int mi = 0; mi < MI; mi++) {
    int mrow = m0 + wm + mi * 16 + lq * 4;
#pragma unroll
    for (int ni = 0; ni < 4; ni++) {
      int ncol = n0 + wn + ni * 16 + lr;
#pragma unroll
      for (int r = 0; r < 4; r++) {
        float y = acc[mi][ni][r];
        int row = mrow + r;
        if (HB) y += bias[row];
        if (OBF) ((__hip_bfloat16*)Cout)[(size_t)row * Ncols + ncol] = __float2bfloat16(y);
        else     ((float*)Cout)[(size_t)row * Ncols + ncol] = y;
      }
    }
  }
}

__global__ __launch_bounds__(256) void k_pw_gemm(
    const __hip_bfloat16* __restrict__ Wpw, const __hip_bfloat16* __restrict__ xnT,
    const float* __restrict__ img_pw_b, const float* __restrict__ wm_pw_b,
    __hip_bfloat16* __restrict__ Y, int ytile0)
{
  int bz = blockIdx.z, t = bz >> 4;
  gemm_core<4, 512, 1024, true, true>(
      Wpw + (size_t)t * C3 * Cch,
      xnT + (size_t)bz * HWp * Cch,
      t ? wm_pw_b : img_pw_b,
      Y + (size_t)bz * C3 * HWp,
      (blockIdx.y + ytile0) * 128);
}

__global__ __launch_bounds__(256) void k_proj_gemm(
    const __hip_bfloat16* __restrict__ projT, const __hip_bfloat16* __restrict__ attnT,
    float* __restrict__ out)
{
  int b = blockIdx.z;
  gemm_core<4, 1024, 1024, false, false>(
      projT, attnT + (size_t)b * HWp * 1024, nullptr, out + (size_t)b * Cch * HWp,
      blockIdx.y * 128);
}

// ---------------- 6. depthwise 3x3 grouped conv, LDS-staged (verified scalar form) ----------------
// Split into 2 dispatches (tb0 = 0,16) for profiler visibility.
__global__ __launch_bounds__(256) void k_dw(
    const __hip_bfloat16* __restrict__ Y,
    const float* __restrict__ img_dw_w, const float* __restrict__ img_dw_b,
    const float* __restrict__ wm_dw_w,  const float* __restrict__ wm_dw_b,
    __hip_bfloat16* __restrict__ QKV, int tb0)
{
  __shared__ __hip_bfloat16 sm[6 * 1024];   // [glch][px], linear (async dest)
  int blk = blockIdx.x;                     // 4096 = 16 tb x 256 gb
  int gb = blk & 255, tb = (blk >> 8) + tb0;
  int tid = threadIdx.x;
  const __hip_bfloat16* src = Y + ((size_t)tb * C3 + gb * 6) * HWp;  // 6 contiguous ch
#pragma unroll
  for (int s = 0; s < 3; s++) {
    int lin = tid + s * 256;                // 768 x 16B = 12KB
    async16(sm + lin * 8, src + lin * 8);
  }
  __syncthreads();                          // vmcnt(0) drain before barrier

  int gl = __builtin_amdgcn_readfirstlane(tid >> 7);   // wave-uniform (2 waves per gl)
  int t  = tid & 127;
  int w0 = (t & 3) * 8;
  int h  = t >> 2;                          // 0..31
  int g  = gb * 2 + gl;
  int tsel = tb >> 4;
  const float* dww = (tsel ? wm_dw_w : img_dw_w) + g * 81;   // 3 o x 27
  const float* dwb = (tsel ? wm_dw_b : img_dw_b) + g * 3;
  float acc[3][8];
#pragma unroll
  for (int o = 0; o < 3; o++) {
    float bv = dwb[o];
#pragma unroll
    for (int w = 0; w < 8; w++) acc[o][w] = bv;
  }
  const bool mlo = (w0 == 0), mhi = (w0 == 24);
#pragma unroll
  for (int i = 0; i < 3; i++) {
#pragma unroll
    for (int kh = 0; kh < 3; kh++) {
      int hh = h + kh - 1;
      if ((unsigned)hh > 31u) continue;
      const __hip_bfloat16* row = sm + (gl * 3 + i) * 1024 + hh * 32;
      bf16x8 c0 = *(const bf16x8*)(row + w0);          // halfs [w0, w0+8), 16B-aligned
      float v[10];
      const unsigned* cu = (const unsigned*)&c0;
#pragma unroll
      for (int j = 0; j < 4; j++) { unsigned u = cu[j]; v[1 + 2*j] = bflo(u); v[2 + 2*j] = bfhi(u); }
      v[0] = mlo ? 0.f : bf1(*(const unsigned short*)(row + w0 - 1));   // half w0-1
      v[9] = mhi ? 0.f : bf1(*(const unsigned short*)(row + w0 + 8));   // half w0+8
#pragma unroll
      for (int o = 0; o < 3; o++) {
        float wk0 = dww[o*27 + i*9 + kh*3 + 0];
        float wk1 = dww[o*27 + i*9 + kh*3 + 1];
        float wk2 = dww[o*27 + i*9 + kh*3 + 2];
#pragma unroll
        for (int w = 0; w < 8; w++)
          acc[o][w] += v[w] * wk0 + v[w + 1] * wk1 + v[w + 2] * wk2;
      }
    }
  }
#pragma unroll
  for (int o = 0; o < 3; o++) {
    union { unsigned short us[8]; uint4 v4; } pk;
#pragma unroll
    for (int w = 0; w < 8; w++) pk.us[w] = f2bf(acc[o][w]);
    *(uint4*)(QKV + ((size_t)tb * C3 + g * 3 + o) * HWp + h * 32 + w0) = pk.v4;
  }
}

// ---------------- 7. attention scores as staged BT-GEMM + softmax over q ----------------
// r7 counters: 45.7 us, MfmaUtil 3%, VALUBusy 4% -> serial HBM-load->MFMA chain, not
// wave-starved. Fix: treat S[k][q] = K[64x1024] x Q^T as a staged GEMM with the
// VERIFIED async16 + XOR-swizzle pattern (gemm_core, MI=NI=2, BK=64, 16 iters).
// Block = (kh, m, b, nh) as before; 4 waves in 2x2 grid; S kept in LDS f32;
// softmax over q per k-row via 4-lane shfl groups; transpose through Ash (verified).
__global__ __launch_bounds__(256) void k_attn_scores(
    const __hip_bfloat16* __restrict__ QKV, __hip_bfloat16* __restrict__ ATg)
{
  __shared__ __hip_bfloat16 As[64 * 64];    // K-tile
  __shared__ __hip_bfloat16 Bs[64 * 64];    // Q-tile
  __shared__ float S[64][65];               // S[k][q]
  __shared__ __hip_bfloat16 Ash[64][72];    // transposed P[q][k]
  int blk = blockIdx.x, kh = blk & 1, m = (blk >> 1) & 1, bn = blk >> 2;
  int b = bn >> 3, nh = bn & 7;
  int tid = threadIdx.x, lane = tid & 63, wv = tid >> 6;
  int lr = lane & 15, lq = lane >> 4;
  const int wm = (wv >> 1) * 32, wn = (wv & 1) * 32;     // 2x2 wave grid, 32x32/wave
  const __hip_bfloat16* Kbase = QKV + (((size_t)(kh * 16 + b)) * C3 + 512 + nh * 64) * HWp;
  const __hip_bfloat16* Qbase = QKV + (((size_t)(m * 16 + b)) * C3 + nh * 64) * HWp;

  f32x4 acc[2][2] = {};
  const int srow = tid >> 3, sslot = tid & 7;
  const int sseg = (sslot ^ (srow & 7)) * 8;    // swizzled global segment (halfs)
  for (int k0 = 0; k0 < HWp; k0 += 64) {
#pragma unroll
    for (int c = 0; c < 2; c++) {
      int row = srow + c * 32;                  // row&7 == srow&7
      async16(&As[row * 64 + sslot * 8], &Kbase[(size_t)row * HWp + k0 + sseg]);
      async16(&Bs[row * 64 + sslot * 8], &Qbase[(size_t)row * HWp + k0 + sseg]);
    }
    __syncthreads();   // compiler emits vmcnt(0) drain here
#pragma unroll
    for (int ks = 0; ks < 2; ks++) {
      bf16x8 af[2], bfr[2];
#pragma unroll
      for (int mi = 0; mi < 2; mi++) {
        int r = wm + mi * 16 + lr;
        af[mi]  = *(const bf16x8*)&As[r * 64 + (((ks * 4 + lq) ^ (lr & 7)) * 8)];
      }
#pragma unroll
      for (int ni = 0; ni < 2; ni++) {
        int r = wn + ni * 16 + lr;
        bfr[ni] = *(const bf16x8*)&Bs[r * 64 + (((ks * 4 + lq) ^ (lr & 7)) * 8)];
      }
#pragma unroll
      for (int mi = 0; mi < 2; mi++)
#pragma unroll
        for (int ni = 0; ni < 2; ni++)
          acc[mi][ni] = __builtin_amdgcn_mfma_f32_16x16x32_bf16(af[mi], bfr[ni], acc[mi][ni], 0, 0, 0);
    }
    __syncthreads();
  }
  // C/D layout: row (A=K-channel) = wm+mi*16+lq*4+r, col (B=q) = wn+ni*16+lr
#pragma unroll
  for (int mi = 0; mi < 2; mi++)
#pragma unroll
    for (int ni = 0; ni < 2; ni++)
#pragma unroll
      for (int r = 0; r < 4; r++)
        S[wm + mi * 16 + lq * 4 + r][wn + ni * 16 + lr] = acc[mi][ni][r];
  __syncthreads();
  // softmax over q (columns) per k row; 4 threads per row, 16 q each
  {
    int k = tid >> 2, qg = tid & 3;
    float v[16], mx = -1e30f;
#pragma unroll
    for (int j = 0; j < 16; j++) { v[j] = S[k][qg * 16 + j]; mx = fmaxf(mx, v[j]); }
    mx = fmaxf(mx, __shfl_xor(mx, 1));
    mx = fmaxf(mx, __shfl_xor(mx, 2));
    float ssum = 0.f;
#pragma unroll
    for (int j = 0; j < 16; j++) { v[j] = __expf(v[j] - mx); ssum += v[j]; }
    ssum += __shfl_xor(ssum, 1);
    ssum += __shfl_xor(ssum, 2);
    float inv = 1.f / ssum;
#pragma unroll
    for (int j = 0; j < 16; j++) Ash[qg * 16 + j][k] = __float2bfloat16(v[j] * inv);
  }
  __syncthreads();
  __hip_bfloat16* outp = ATg + ((size_t)(bn * 2 + m)) * 64 * 128 + kh * 64;
#pragma unroll
  for (int s = 0; s < 2; s++) {
    int id = tid + s * 256, row = id >> 3, seg = (id & 7) * 8;
    *(uint4*)&outp[(size_t)row * 128 + seg] = *(const uint4*)&Ash[row][seg];
  }
}

// ---------------- 8. attention output ----------------
__global__ __launch_bounds__(256) void k_attn_out(
    const __hip_bfloat16* __restrict__ QKV, const __hip_bfloat16* __restrict__ ATg,
    __hip_bfloat16* __restrict__ attnT)
{
  int blk = blockIdx.x, pc = blk & 3, bn = blk >> 2, b = bn >> 3, nh = bn & 7;
  int tid = threadIdx.x, lane = tid & 63, wv = tid >> 6;
  int lr = lane & 15, lq = lane >> 4;
  __shared__ __hip_bfloat16 ATs[2][64][136];
  __shared__ __hip_bfloat16 VTs[64][136];
#pragma unroll
  for (int m = 0; m < 2; m++) {
    const __hip_bfloat16* src = ATg + ((size_t)(bn * 2 + m)) * 64 * 128;
#pragma unroll
    for (int s = 0; s < 4; s++) {
      int id = tid + s * 256, row = id >> 4, seg = (id & 15) * 8;
      *(uint4*)&ATs[m][row][seg] = *(const uint4*)&src[row * 128 + seg];
    }
  }
  const int vk0 = (tid >> 3) * 4, vps = (tid & 7) * 8;
  for (int ps = 0; ps < 4; ps++) {
    int p0 = pc * 256 + ps * 64;
    __syncthreads();
    union { uint4 v4; unsigned short us[8]; } ld[4];
#pragma unroll
    for (int j = 0; j < 4; j++) {
      int kk = vk0 + j, tk = kk >> 6, hc = kk & 63;
      ld[j].v4 = *(const uint4*)(QKV +
          (((size_t)(tk * 16 + b)) * C3 + 1024 + nh * 64 + hc) * HWp + p0 + vps);
    }
#pragma unroll
    for (int e = 0; e < 8; e++) {
      uint2 w;
      w.x = (unsigned)ld[0].us[e] | ((unsigned)ld[1].us[e] << 16);
      w.y = (unsigned)ld[2].us[e] | ((unsigned)ld[3].us[e] << 16);
      *(uint2*)&VTs[vps + e][vk0] = w;
    }
    __syncthreads();
#pragma unroll
    for (int m = 0; m < 2; m++) {
      f32x4 oacc[4] = {};
#pragma unroll
      for (int ks = 0; ks < 4; ks++) {
        bf16x8 bv = *(const bf16x8*)&VTs[wv * 16 + lr][ks * 32 + lq * 8];
#pragma unroll
        for (int qt = 0; qt < 4; qt++) {
          bf16x8 av = *(const bf16x8*)&ATs[m][qt * 16 + lr][ks * 32 + lq * 8];
          oacc[qt] = __builtin_amdgcn_mfma_f32_16x16x32_bf16(av, bv, oacc[qt], 0, 0, 0);
        }
      }
#pragma unroll
      for (int qt = 0; qt < 4; qt++) {
        int q = qt * 16 + lq * 4;
        int d = nh * 128 + m * 64 + q;
        int p = p0 + wv * 16 + lr;
        union { unsigned short us[4]; uint2 v2; } pk;
#pragma unroll
        for (int r = 0; r < 4; r++) pk.us[r] = f2bf(oacc[qt][r]);
        *(uint2*)&attnT[((size_t)b * HWp + p) * 1024 + d] = pk.v2;
      }
    }
  }
}

extern "C" void kernel_launch(void* const* d_in, const int* in_sizes, int n_in,
                              void* d_out, int out_size, void* d_ws, size_t ws_size,
                              hipStream_t stream)
{
  (void)in_sizes; (void)n_in; (void)out_size; (void)ws_size;
  const float* image     = (const float*)d_in[0];
  const float* watermark = (const float*)d_in[1];
  const float* img_ln_w  = (const float*)d_in[2];
  const float* img_ln_b  = (const float*)d_in[3];
  const float* wm_ln_w   = (const float*)d_in[4];
  const float* wm_ln_b   = (const float*)d_in[5];
  const float* img_pw_w  = (const float*)d_in[6];
  const float* img_pw_b  = (const float*)d_in[7];
  const float* img_dw_w  = (const float*)d_in[8];
  const float* img_dw_b  = (const float*)d_in[9];
  const float* wm_pw_w   = (const float*)d_in[10];
  const float* wm_pw_b   = (const float*)d_in[11];
  const float* wm_dw_w   = (const float*)d_in[12];
  const float* wm_dw_b   = (const float*)d_in[13];
  const float* proj      = (const float*)d_in[14];

  char* ws = (char*)d_ws;
  // workspace map (high-water ~232 MiB); aliases are lifetime-disjoint:
  //   attnT aliases xnT (xnT dead after k_pw_gemm); ATg aliases Y (Y dead after k_dw)
  __hip_bfloat16* Wpw    = (__hip_bfloat16*)(ws + 0);            // 3.0 MiB
  __hip_bfloat16* projT  = (__hip_bfloat16*)(ws + 3145728);      // 1.0 MiB
  float*          lnpart = (float*)(ws + 4194304);               // 16 KiB
  __hip_bfloat16* xnT    = (__hip_bfloat16*)(ws + 5242880);      // 32 MiB
  __hip_bfloat16* attnT  = xnT;                                  // alias
  __hip_bfloat16* Y      = (__hip_bfloat16*)(ws + 41943040);     // 96 MiB
  __hip_bfloat16* ATg    = Y;                                    // alias (4 MiB)
  __hip_bfloat16* QKV    = (__hip_bfloat16*)(ws + 142606336);    // 96 MiB

  k_prep_ln<<<5632, 256, 0, stream>>>(img_pw_w, wm_pw_w, proj, image, watermark,
                                      Wpw, projT, lnpart);
  k_norm_t<<<8192, 256, 0, stream>>>(image, watermark, img_ln_w, img_ln_b,
                                     wm_ln_w, wm_ln_b, lnpart, xnT);
  dim3 gpw(8, 6, 32);
  k_pw_gemm<<<gpw, 256, 0, stream>>>(Wpw, xnT, img_pw_b, wm_pw_b, Y, 0);
  k_pw_gemm<<<gpw, 256, 0, stream>>>(Wpw, xnT, img_pw_b, wm_pw_b, Y, 6);
  k_dw<<<4096, 256, 0, stream>>>(Y, img_dw_w, img_dw_b, wm_dw_w, wm_dw_b, QKV, 0);
  k_dw<<<4096, 256, 0, stream>>>(Y, img_dw_w, img_dw_b, wm_dw_w, wm_dw_b, QKV, 16);
  k_attn_scores<<<512, 256, 0, stream>>>(QKV, ATg);
  k_attn_out<<<512, 256, 0, stream>>>(QKV, ATg, attnT);
  dim3 gpj(8, 4, 16);
  k_proj_gemm<<<gpj, 256, 0, stream>>>(projT, attnT, (float*)d_out);
}

// Round 9
// 369.132 us; speedup vs baseline: 1.0310x; 1.0083x over previous
//
#include <hip/hip_runtime.h>
#include <hip/hip_bf16.h>
#include <stdint.h>

// Problem dims: B=16, C=512, H=W=32, NH=8, HC=64, HW=1024, 3C=1536
#define Bn  16
#define Cch 512
#define C3  1536
#define HWp 1024

typedef __attribute__((ext_vector_type(8))) short bf16x8;    // 8 bf16 = 4 VGPRs (MFMA A/B frag)
typedef __attribute__((ext_vector_type(4))) float f32x4;     // 16x16 MFMA C/D frag

#define DEV static __device__ __forceinline__

DEV float bflo(unsigned u) { return __builtin_bit_cast(float, u << 16); }
DEV float bfhi(unsigned u) { return __builtin_bit_cast(float, u & 0xffff0000u); }
DEV float bf1(unsigned short us) { return __builtin_bit_cast(float, (unsigned)us << 16); }
DEV unsigned short f2bf(float f) {
  __hip_bfloat16 h = __float2bfloat16(f);
  return __builtin_bit_cast(unsigned short, h);
}

// async global->LDS, 16B per lane. LDS dest must be wave-uniform base + lane*16.
DEV void async16(__hip_bfloat16* lds, const __hip_bfloat16* g) {
  __builtin_amdgcn_global_load_lds(
      (const __attribute__((address_space(1))) unsigned*)g,
      (__attribute__((address_space(3))) unsigned*)lds, 16, 0, 0);
}

// ---------------- 1. weight prep (fp32->bf16, vectorized) + LayerNorm partial sums ----------------
// blocks [0,1536): pw-weight cast as float4->bf16x4 (393216 float4)
// blocks [1536,3584): proj transpose (scalar reads, coalesced writes)
// blocks [3584,5632): ln partial (2048 = t*1024 + b*64 + chunk)
__global__ __launch_bounds__(256) void k_prep_ln(
    const float* __restrict__ img_pw_w, const float* __restrict__ wm_pw_w,
    const float* __restrict__ proj,
    const float* __restrict__ image, const float* __restrict__ watermark,
    __hip_bfloat16* __restrict__ Wpw, __hip_bfloat16* __restrict__ projT,
    float* __restrict__ part)
{
  __shared__ float ls[4], lss[4];
  int blkid = blockIdx.x;
  if (blkid < 1536) {
    int i = blkid * 256 + threadIdx.x;      // float4 index, 0..393215
    const int NW4 = (C3 * Cch) / 4;         // 196608
    const float4* srcv = (i < NW4) ? (const float4*)img_pw_w : (const float4*)wm_pw_w;
    int j = (i < NW4) ? i : i - NW4;
    float4 v = srcv[j];
    ushort4 o = { f2bf(v.x), f2bf(v.y), f2bf(v.z), f2bf(v.w) };
    ((ushort4*)Wpw)[i] = o;
    return;
  }
  if (blkid < 3584) {
    int j = (blkid - 1536) * 256 + threadIdx.x;   // 0..524287
    int c = j >> 10, d = j & 1023;
    projT[(size_t)c * 1024 + d] = __float2bfloat16(proj[(size_t)d * 512 + c]);
    return;
  }
  int blk = blkid - 3584;
  int chunk = blk & 63, b = (blk >> 6) & 15, t = blk >> 10;
  const float* x = (t ? watermark : image) + (size_t)b * Cch * HWp + chunk * 8192;
  const float4* xv = (const float4*)x;
  float s = 0.f, ss = 0.f;
#pragma unroll
  for (int i = 0; i < 8; i++) {
    float4 v = xv[threadIdx.x + i * 256];
    s  += v.x + v.y + v.z + v.w;
    ss += v.x * v.x + v.y * v.y + v.z * v.z + v.w * v.w;
  }
#pragma unroll
  for (int off = 32; off; off >>= 1) { s += __shfl_down(s, off); ss += __shfl_down(ss, off); }
  int wv = threadIdx.x >> 6;
  if ((threadIdx.x & 63) == 0) { ls[wv] = s; lss[wv] = ss; }
  __syncthreads();
  if (threadIdx.x == 0) {
    part[blk * 2]     = ls[0] + ls[1] + ls[2] + ls[3];
    part[blk * 2 + 1] = lss[0] + lss[1] + lss[2] + lss[3];
  }
}

// ---------------- 4. normalize + affine + transpose -> xnT[t][b][p][c] bf16 ----------------
// (ln finalize folded in: wave 0 reduces this (t,b)'s 64 partial pairs)
__global__ __launch_bounds__(256) void k_norm_t(
    const float* __restrict__ image, const float* __restrict__ watermark,
    const float* __restrict__ img_w, const float* __restrict__ img_b,
    const float* __restrict__ wm_w,  const float* __restrict__ wm_b,
    const float* __restrict__ part, __hip_bfloat16* __restrict__ xnT)
{
  int blk = blockIdx.x;
  int ct = blk & 15, pt = (blk >> 4) & 15, b = (blk >> 8) & 15, t = blk >> 12;
  int c0 = ct * 32, p0 = pt * 64;
  const float* x   = (t ? watermark : image) + (size_t)b * Cch * HWp;
  const float* wgt = t ? wm_w : img_w;
  const float* bia = t ? wm_b : img_b;
  int tid = threadIdx.x;
  __shared__ float sst[2];
  if (tid < 64) {
    float S  = part[(t * 1024 + b * 64 + tid) * 2];
    float SS = part[(t * 1024 + b * 64 + tid) * 2 + 1];
#pragma unroll
    for (int off = 32; off; off >>= 1) { S += __shfl_down(S, off); SS += __shfl_down(SS, off); }
    if (tid == 0) {
      const float inv = 1.f / (float)(Cch * HWp);
      float mu  = S * inv;
      float var = SS * inv - mu * mu;
      sst[0] = mu;
      sst[1] = rsqrtf(var + 1e-5f);
    }
  }
  __syncthreads();
  float mu = sst[0], rstd = sst[1];
  __shared__ float tile[32 * 66];
  {
    int c = tid >> 3, s = tid & 7;
    const float* xr = x   + (size_t)(c0 + c) * HWp + p0;
    const float* wr = wgt + (size_t)(c0 + c) * HWp + p0;
    const float* br = bia + (size_t)(c0 + c) * HWp + p0;
#pragma unroll
    for (int j = 0; j < 2; j++) {
      int f = s + j * 8;                 // float4 slot 0..15
      float4 xv = *(const float4*)&xr[f * 4];
      float4 wv = *(const float4*)&wr[f * 4];
      float4 bv = *(const float4*)&br[f * 4];
      float n0 = (xv.x - mu) * rstd * wv.x + bv.x;
      float n1 = (xv.y - mu) * rstd * wv.y + bv.y;
      float n2 = (xv.z - mu) * rstd * wv.z + bv.z;
      float n3 = (xv.w - mu) * rstd * wv.w + bv.w;
      *(float2*)&tile[c * 66 + f * 4]     = make_float2(n0, n1);
      *(float2*)&tile[c * 66 + f * 4 + 2] = make_float2(n2, n3);
    }
  }
  __syncthreads();
  {
    int p = tid >> 2, cq = tid & 3;      // 64 p x 4 c-groups of 8
    union { unsigned short us[8]; uint4 v4; } pk;
#pragma unroll
    for (int j = 0; j < 8; j++) pk.us[j] = f2bf(tile[(cq * 8 + j) * 66 + p]);
    __hip_bfloat16* dst = xnT + ((size_t)(t * 16 + b)) * HWp * Cch
                        + (size_t)(p0 + p) * Cch + c0 + cq * 8;
    *(uint4*)dst = pk.v4;
  }
}

// ---------------- 5. bf16 BT-GEMM core: 16x16x32 MFMA + XOR-swizzled LDS ----------------
template<int MI, int Kdim, int Ncols, bool OBF, bool HB>
DEV void gemm_core(const __hip_bfloat16* __restrict__ A,
                   const __hip_bfloat16* __restrict__ Bt,
                   const float* __restrict__ bias, void* __restrict__ Cout, int m0)
{
  constexpr int MT = MI * 32;
  __shared__ __hip_bfloat16 As[MT * 64];
  __shared__ __hip_bfloat16 Bs[128 * 64];
  const int tid = threadIdx.x, lane = tid & 63, wv = tid >> 6;
  const int lr = lane & 15, lq = lane >> 4;
  const int wm = (wv >> 1) * (MI * 16), wn = (wv & 1) * 64;
  const int n0 = blockIdx.x * 128;
  f32x4 acc[MI][4] = {};
  const int srow = tid >> 3, sslot = tid & 7;
  const int sseg = (sslot ^ (srow & 7)) * 8;    // swizzled global segment (halfs)
  for (int k0 = 0; k0 < Kdim; k0 += 64) {
#pragma unroll
    for (int c = 0; c < MI; c++) {
      int row = srow + c * 32;                  // row&7 == srow&7 (c*32 mult of 8)
      async16(&As[row * 64 + sslot * 8], &A[(size_t)(m0 + row) * Kdim + k0 + sseg]);
    }
#pragma unroll
    for (int c = 0; c < 4; c++) {
      int row = srow + c * 32;
      async16(&Bs[row * 64 + sslot * 8], &Bt[(size_t)(n0 + row) * Kdim + k0 + sseg]);
    }
    __syncthreads();   // compiler emits vmcnt(0) drain here
#pragma unroll
    for (int ks = 0; ks < 2; ks++) {
      bf16x8 af[MI], bfr[4];
#pragma unroll
      for (int mi = 0; mi < MI; mi++) {
        int r = wm + mi * 16 + lr;              // r&7 == lr&7
        af[mi]  = *(const bf16x8*)&As[r * 64 + (((ks * 4 + lq) ^ (lr & 7)) * 8)];
      }
#pragma unroll
      for (int ni = 0; ni < 4; ni++) {
        int r = wn + ni * 16 + lr;
        bfr[ni] = *(const bf16x8*)&Bs[r * 64 + (((ks * 4 + lq) ^ (lr & 7)) * 8)];
      }
#pragma unroll
      for (int mi = 0; mi < MI; mi++)
#pragma unroll
        for (int ni = 0; ni < 4; ni++)
          acc[mi][ni] = __builtin_amdgcn_mfma_f32_16x16x32_bf16(af[mi], bfr[ni], acc[mi][ni], 0, 0, 0);
    }
    __syncthreads();
  }
#pragma unroll
  for (int mi = 0; mi < MI; mi++) {
    int mrow = m0 + wm + mi * 16 + lq * 4;
#pragma unroll
    for (int ni = 0; ni < 4; ni++) {
      int ncol = n0 + wn + ni * 16 + lr;
#pragma unroll
      for (int r = 0; r < 4; r++) {
        float y = acc[mi][ni][r];
        int row = mrow + r;
        if (HB) y += bias[row];
        if (OBF) ((__hip_bfloat16*)Cout)[(size_t)row * Ncols + ncol] = __float2bfloat16(y);
        else     ((float*)Cout)[(size_t)row * Ncols + ncol] = y;
      }
    }
  }
}

__global__ __launch_bounds__(256) void k_pw_gemm(
    const __hip_bfloat16* __restrict__ Wpw, const __hip_bfloat16* __restrict__ xnT,
    const float* __restrict__ img_pw_b, const float* __restrict__ wm_pw_b,
    __hip_bfloat16* __restrict__ Y, int ytile0)
{
  int bz = blockIdx.z, t = bz >> 4;
  gemm_core<4, 512, 1024, true, true>(
      Wpw + (size_t)t * C3 * Cch,
      xnT + (size_t)bz * HWp * Cch,
      t ? wm_pw_b : img_pw_b,
      Y + (size_t)bz * C3 * HWp,
      (blockIdx.y + ytile0) * 128);
}

__global__ __launch_bounds__(256) void k_proj_gemm(
    const __hip_bfloat16* __restrict__ projT, const __hip_bfloat16* __restrict__ attnT,
    float* __restrict__ out)
{
  int b = blockIdx.z;
  gemm_core<4, 1024, 1024, false, false>(
      projT, attnT + (size_t)b * HWp * 1024, nullptr, out + (size_t)b * Cch * HWp,
      blockIdx.y * 128);
}

// ---------------- 6. depthwise 3x3 grouped conv, LDS-staged (verified scalar form) ----------------
// Split into 2 dispatches (tb0 = 0,16) for profiler visibility.
__global__ __launch_bounds__(256) void k_dw(
    const __hip_bfloat16* __restrict__ Y,
    const float* __restrict__ img_dw_w, const float* __restrict__ img_dw_b,
    const float* __restrict__ wm_dw_w,  const float* __restrict__ wm_dw_b,
    __hip_bfloat16* __restrict__ QKV, int tb0)
{
  __shared__ __hip_bfloat16 sm[6 * 1024];   // [glch][px], linear (async dest)
  int blk = blockIdx.x;                     // 4096 = 16 tb x 256 gb
  int gb = blk & 255, tb = (blk >> 8) + tb0;
  int tid = threadIdx.x;
  const __hip_bfloat16* src = Y + ((size_t)tb * C3 + gb * 6) * HWp;  // 6 contiguous ch
#pragma unroll
  for (int s = 0; s < 3; s++) {
    int lin = tid + s * 256;                // 768 x 16B = 12KB
    async16(sm + lin * 8, src + lin * 8);
  }
  __syncthreads();                          // vmcnt(0) drain before barrier

  int gl = __builtin_amdgcn_readfirstlane(tid >> 7);   // wave-uniform (2 waves per gl)
  int t  = tid & 127;
  int w0 = (t & 3) * 8;
  int h  = t >> 2;                          // 0..31
  int g  = gb * 2 + gl;
  int tsel = tb >> 4;
  const float* dww = (tsel ? wm_dw_w : img_dw_w) + g * 81;   // 3 o x 27
  const float* dwb = (tsel ? wm_dw_b : img_dw_b) + g * 3;
  float acc[3][8];
#pragma unroll
  for (int o = 0; o < 3; o++) {
    float bv = dwb[o];
#pragma unroll
    for (int w = 0; w < 8; w++) acc[o][w] = bv;
  }
  const bool mlo = (w0 == 0), mhi = (w0 == 24);
#pragma unroll
  for (int i = 0; i < 3; i++) {
#pragma unroll
    for (int kh = 0; kh < 3; kh++) {
      int hh = h + kh - 1;
      if ((unsigned)hh > 31u) continue;
      const __hip_bfloat16* row = sm + (gl * 3 + i) * 1024 + hh * 32;
      bf16x8 c0 = *(const bf16x8*)(row + w0);          // halfs [w0, w0+8), 16B-aligned
      float v[10];
      const unsigned* cu = (const unsigned*)&c0;
#pragma unroll
      for (int j = 0; j < 4; j++) { unsigned u = cu[j]; v[1 + 2*j] = bflo(u); v[2 + 2*j] = bfhi(u); }
      v[0] = mlo ? 0.f : bf1(*(const unsigned short*)(row + w0 - 1));   // half w0-1
      v[9] = mhi ? 0.f : bf1(*(const unsigned short*)(row + w0 + 8));   // half w0+8
#pragma unroll
      for (int o = 0; o < 3; o++) {
        float wk0 = dww[o*27 + i*9 + kh*3 + 0];
        float wk1 = dww[o*27 + i*9 + kh*3 + 1];
        float wk2 = dww[o*27 + i*9 + kh*3 + 2];
#pragma unroll
        for (int w = 0; w < 8; w++)
          acc[o][w] += v[w] * wk0 + v[w + 1] * wk1 + v[w + 2] * wk2;
      }
    }
  }
#pragma unroll
  for (int o = 0; o < 3; o++) {
    union { unsigned short us[8]; uint4 v4; } pk;
#pragma unroll
    for (int w = 0; w < 8; w++) pk.us[w] = f2bf(acc[o][w]);
    *(uint4*)(QKV + ((size_t)tb * C3 + g * 3 + o) * HWp + h * 32 + w0) = pk.v4;
  }
}

// ---------------- 7. attention scores as staged BT-GEMM + softmax over q ----------------
// r8: GEMM form landed ~40 us (out of top-5 but total barely moved) -- grid 512 blocks
// = 2 blocks/CU x 4 waves = 8 waves/CU: staging drains unhidden. This round: 512 thr
// = 8 waves (2x4 wave grid over the 64x64 tile), same verified staging (each thread
// exactly ONE async16 per buffer: 512 x 16B = 8KB tile; LDS offset = tid*16B keeps
// the linear-dest constraint). 16 waves/CU.
__global__ __launch_bounds__(512) void k_attn_scores(
    const __hip_bfloat16* __restrict__ QKV, __hip_bfloat16* __restrict__ ATg)
{
  __shared__ __hip_bfloat16 As[64 * 64];    // K-tile
  __shared__ __hip_bfloat16 Bs[64 * 64];    // Q-tile
  __shared__ float S[64][65];               // S[k][q]
  __shared__ __hip_bfloat16 Ash[64][72];    // transposed P[q][k]
  int blk = blockIdx.x, kh = blk & 1, m = (blk >> 1) & 1, bn = blk >> 2;
  int b = bn >> 3, nh = bn & 7;
  int tid = threadIdx.x, lane = tid & 63, wv8 = tid >> 6;
  int lr = lane & 15, lq = lane >> 4;
  const int wm = (wv8 >> 2) * 32, wn = (wv8 & 3) * 16;   // 2x4 wave grid, 32x16/wave
  const __hip_bfloat16* Kbase = QKV + (((size_t)(kh * 16 + b)) * C3 + 512 + nh * 64) * HWp;
  const __hip_bfloat16* Qbase = QKV + (((size_t)(m * 16 + b)) * C3 + nh * 64) * HWp;

  f32x4 acc[2] = {};
  const int srow = tid >> 3, sslot = tid & 7;   // 512 thr: srow 0..63
  const int sseg = (sslot ^ (srow & 7)) * 8;    // swizzled global segment (halfs)
  for (int k0 = 0; k0 < HWp; k0 += 64) {
    async16(&As[srow * 64 + sslot * 8], &Kbase[(size_t)srow * HWp + k0 + sseg]);
    async16(&Bs[srow * 64 + sslot * 8], &Qbase[(size_t)srow * HWp + k0 + sseg]);
    __syncthreads();   // compiler emits vmcnt(0) drain here
#pragma unroll
    for (int ks = 0; ks < 2; ks++) {
      bf16x8 af[2], bfr;
#pragma unroll
      for (int mi = 0; mi < 2; mi++) {
        int r = wm + mi * 16 + lr;              // r&7 == lr&7 (wm,16 mult of 8)
        af[mi]  = *(const bf16x8*)&As[r * 64 + (((ks * 4 + lq) ^ (lr & 7)) * 8)];
      }
      {
        int r = wn + lr;                        // wn mult of 8
        bfr = *(const bf16x8*)&Bs[r * 64 + (((ks * 4 + lq) ^ (lr & 7)) * 8)];
      }
#pragma unroll
      for (int mi = 0; mi < 2; mi++)
        acc[mi] = __builtin_amdgcn_mfma_f32_16x16x32_bf16(af[mi], bfr, acc[mi], 0, 0, 0);
    }
    __syncthreads();
  }
  // C/D layout: row (A=K-channel) = wm+mi*16+lq*4+r, col (B=q) = wn+lr
#pragma unroll
  for (int mi = 0; mi < 2; mi++)
#pragma unroll
    for (int r = 0; r < 4; r++)
      S[wm + mi * 16 + lq * 4 + r][wn + lr] = acc[mi][r];
  __syncthreads();
  // softmax over q (columns) per k row; 8 threads per row, 8 q each
  {
    int k = tid >> 3, qg = tid & 7;
    float v[8], mx = -1e30f;
#pragma unroll
    for (int j = 0; j < 8; j++) { v[j] = S[k][qg * 8 + j]; mx = fmaxf(mx, v[j]); }
    mx = fmaxf(mx, __shfl_xor(mx, 1));
    mx = fmaxf(mx, __shfl_xor(mx, 2));
    mx = fmaxf(mx, __shfl_xor(mx, 4));
    float ssum = 0.f;
#pragma unroll
    for (int j = 0; j < 8; j++) { v[j] = __expf(v[j] - mx); ssum += v[j]; }
    ssum += __shfl_xor(ssum, 1);
    ssum += __shfl_xor(ssum, 2);
    ssum += __shfl_xor(ssum, 4);
    float inv = 1.f / ssum;
#pragma unroll
    for (int j = 0; j < 8; j++) Ash[qg * 8 + j][k] = __float2bfloat16(v[j] * inv);
  }
  __syncthreads();
  __hip_bfloat16* outp = ATg + ((size_t)(bn * 2 + m)) * 64 * 128 + kh * 64;
  {
    int row = tid >> 3, seg = (tid & 7) * 8;
    *(uint4*)&outp[(size_t)row * 128 + seg] = *(const uint4*)&Ash[row][seg];
  }
}

// ---------------- 8. attention output ----------------
__global__ __launch_bounds__(256) void k_attn_out(
    const __hip_bfloat16* __restrict__ QKV, const __hip_bfloat16* __restrict__ ATg,
    __hip_bfloat16* __restrict__ attnT)
{
  int blk = blockIdx.x, pc = blk & 3, bn = blk >> 2, b = bn >> 3, nh = bn & 7;
  int tid = threadIdx.x, lane = tid & 63, wv = tid >> 6;
  int lr = lane & 15, lq = lane >> 4;
  __shared__ __hip_bfloat16 ATs[2][64][136];
  __shared__ __hip_bfloat16 VTs[64][136];
#pragma unroll
  for (int m = 0; m < 2; m++) {
    const __hip_bfloat16* src = ATg + ((size_t)(bn * 2 + m)) * 64 * 128;
#pragma unroll
    for (int s = 0; s < 4; s++) {
      int id = tid + s * 256, row = id >> 4, seg = (id & 15) * 8;
      *(uint4*)&ATs[m][row][seg] = *(const uint4*)&src[row * 128 + seg];
    }
  }
  const int vk0 = (tid >> 3) * 4, vps = (tid & 7) * 8;
  for (int ps = 0; ps < 4; ps++) {
    int p0 = pc * 256 + ps * 64;
    __syncthreads();
    union { uint4 v4; unsigned short us[8]; } ld[4];
#pragma unroll
    for (int j = 0; j < 4; j++) {
      int kk = vk0 + j, tk = kk >> 6, hc = kk & 63;
      ld[j].v4 = *(const uint4*)(QKV +
          (((size_t)(tk * 16 + b)) * C3 + 1024 + nh * 64 + hc) * HWp + p0 + vps);
    }
#pragma unroll
    for (int e = 0; e < 8; e++) {
      uint2 w;
      w.x = (unsigned)ld[0].us[e] | ((unsigned)ld[1].us[e] << 16);
      w.y = (unsigned)ld[2].us[e] | ((unsigned)ld[3].us[e] << 16);
      *(uint2*)&VTs[vps + e][vk0] = w;
    }
    __syncthreads();
#pragma unroll
    for (int m = 0; m < 2; m++) {
      f32x4 oacc[4] = {};
#pragma unroll
      for (int ks = 0; ks < 4; ks++) {
        bf16x8 bv = *(const bf16x8*)&VTs[wv * 16 + lr][ks * 32 + lq * 8];
#pragma unroll
        for (int qt = 0; qt < 4; qt++) {
          bf16x8 av = *(const bf16x8*)&ATs[m][qt * 16 + lr][ks * 32 + lq * 8];
          oacc[qt] = __builtin_amdgcn_mfma_f32_16x16x32_bf16(av, bv, oacc[qt], 0, 0, 0);
        }
      }
#pragma unroll
      for (int qt = 0; qt < 4; qt++) {
        int q = qt * 16 + lq * 4;
        int d = nh * 128 + m * 64 + q;
        int p = p0 + wv * 16 + lr;
        union { unsigned short us[4]; uint2 v2; } pk;
#pragma unroll
        for (int r = 0; r < 4; r++) pk.us[r] = f2bf(oacc[qt][r]);
        *(uint2*)&attnT[((size_t)b * HWp + p) * 1024 + d] = pk.v2;
      }
    }
  }
}

extern "C" void kernel_launch(void* const* d_in, const int* in_sizes, int n_in,
                              void* d_out, int out_size, void* d_ws, size_t ws_size,
                              hipStream_t stream)
{
  (void)in_sizes; (void)n_in; (void)out_size; (void)ws_size;
  const float* image     = (const float*)d_in[0];
  const float* watermark = (const float*)d_in[1];
  const float* img_ln_w  = (const float*)d_in[2];
  const float* img_ln_b  = (const float*)d_in[3];
  const float* wm_ln_w   = (const float*)d_in[4];
  const float* wm_ln_b   = (const float*)d_in[5];
  const float* img_pw_w  = (const float*)d_in[6];
  const float* img_pw_b  = (const float*)d_in[7];
  const float* img_dw_w  = (const float*)d_in[8];
  const float* img_dw_b  = (const float*)d_in[9];
  const float* wm_pw_w   = (const float*)d_in[10];
  const float* wm_pw_b   = (const float*)d_in[11];
  const float* wm_dw_w   = (const float*)d_in[12];
  const float* wm_dw_b   = (const float*)d_in[13];
  const float* proj      = (const float*)d_in[14];

  char* ws = (char*)d_ws;
  // workspace map (high-water ~232 MiB); aliases are lifetime-disjoint:
  //   attnT aliases xnT (xnT dead after k_pw_gemm); ATg aliases Y (Y dead after k_dw)
  __hip_bfloat16* Wpw    = (__hip_bfloat16*)(ws + 0);            // 3.0 MiB
  __hip_bfloat16* projT  = (__hip_bfloat16*)(ws + 3145728);      // 1.0 MiB
  float*          lnpart = (float*)(ws + 4194304);               // 16 KiB
  __hip_bfloat16* xnT    = (__hip_bfloat16*)(ws + 5242880);      // 32 MiB
  __hip_bfloat16* attnT  = xnT;                                  // alias
  __hip_bfloat16* Y      = (__hip_bfloat16*)(ws + 41943040);     // 96 MiB
  __hip_bfloat16* ATg    = Y;                                    // alias (4 MiB)
  __hip_bfloat16* QKV    = (__hip_bfloat16*)(ws + 142606336);    // 96 MiB

  k_prep_ln<<<5632, 256, 0, stream>>>(img_pw_w, wm_pw_w, proj, image, watermark,
                                      Wpw, projT, lnpart);
  k_norm_t<<<8192, 256, 0, stream>>>(image, watermark, img_ln_w, img_ln_b,
                                     wm_ln_w, wm_ln_b, lnpart, xnT);
  dim3 gpw(8, 6, 32);
  k_pw_gemm<<<gpw, 256, 0, stream>>>(Wpw, xnT, img_pw_b, wm_pw_b, Y, 0);
  k_pw_gemm<<<gpw, 256, 0, stream>>>(Wpw, xnT, img_pw_b, wm_pw_b, Y, 6);
  k_dw<<<4096, 256, 0, stream>>>(Y, img_dw_w, img_dw_b, wm_dw_w, wm_dw_b, QKV, 0);
  k_dw<<<4096, 256, 0, stream>>>(Y, img_dw_w, img_dw_b, wm_dw_w, wm_dw_b, QKV, 16);
  k_attn_scores<<<512, 512, 0, stream>>>(QKV, ATg);
  k_attn_out<<<512, 256, 0, stream>>>(QKV, ATg, attnT);
  dim3 gpj(8, 4, 16);
  k_proj_gemm<<<gpj, 256, 0, stream>>>(projT, attnT, (float*)d_out);
}

// Round 10
// 345.071 us; speedup vs baseline: 1.1029x; 1.0697x over previous
//
#include <hip/hip_runtime.h>
#include <hip/hip_bf16.h>
#include <stdint.h>

// Problem dims: B=16, C=512, H=W=32, NH=8, HC=64, HW=1024, 3C=1536
#define Bn  16
#define Cch 512
#define C3  1536
#define HWp 1024

typedef __attribute__((ext_vector_type(8))) short bf16x8;    // 8 bf16 = 4 VGPRs (MFMA A/B frag)
typedef __attribute__((ext_vector_type(4))) float f32x4;     // 16x16 MFMA C/D frag

#define DEV static __device__ __forceinline__

DEV float bflo(unsigned u) { return __builtin_bit_cast(float, u << 16); }
DEV float bfhi(unsigned u) { return __builtin_bit_cast(float, u & 0xffff0000u); }
DEV float bf1(unsigned short us) { return __builtin_bit_cast(float, (unsigned)us << 16); }
DEV unsigned short f2bf(float f) {
  __hip_bfloat16 h = __float2bfloat16(f);
  return __builtin_bit_cast(unsigned short, h);
}

// async global->LDS, 16B per lane. LDS dest must be wave-uniform base + lane*16.
DEV void async16(__hip_bfloat16* lds, const __hip_bfloat16* g) {
  __builtin_amdgcn_global_load_lds(
      (const __attribute__((address_space(1))) unsigned*)g,
      (__attribute__((address_space(3))) unsigned*)lds, 16, 0, 0);
}

// ---------------- 1. weight prep (fp32->bf16, vectorized) + LayerNorm partial sums ----------------
// blocks [0,1536): pw-weight cast as float4->bf16x4 (393216 float4)
// blocks [1536,3584): proj transpose (scalar reads, coalesced writes)
// blocks [3584,5632): ln partial (2048 = t*1024 + b*64 + chunk)
__global__ __launch_bounds__(256) void k_prep_ln(
    const float* __restrict__ img_pw_w, const float* __restrict__ wm_pw_w,
    const float* __restrict__ proj,
    const float* __restrict__ image, const float* __restrict__ watermark,
    __hip_bfloat16* __restrict__ Wpw, __hip_bfloat16* __restrict__ projT,
    float* __restrict__ part)
{
  __shared__ float ls[4], lss[4];
  int blkid = blockIdx.x;
  if (blkid < 1536) {
    int i = blkid * 256 + threadIdx.x;      // float4 index, 0..393215
    const int NW4 = (C3 * Cch) / 4;         // 196608
    const float4* srcv = (i < NW4) ? (const float4*)img_pw_w : (const float4*)wm_pw_w;
    int j = (i < NW4) ? i : i - NW4;
    float4 v = srcv[j];
    ushort4 o = { f2bf(v.x), f2bf(v.y), f2bf(v.z), f2bf(v.w) };
    ((ushort4*)Wpw)[i] = o;
    return;
  }
  if (blkid < 3584) {
    int j = (blkid - 1536) * 256 + threadIdx.x;   // 0..524287
    int c = j >> 10, d = j & 1023;
    projT[(size_t)c * 1024 + d] = __float2bfloat16(proj[(size_t)d * 512 + c]);
    return;
  }
  int blk = blkid - 3584;
  int chunk = blk & 63, b = (blk >> 6) & 15, t = blk >> 10;
  const float* x = (t ? watermark : image) + (size_t)b * Cch * HWp + chunk * 8192;
  const float4* xv = (const float4*)x;
  float s = 0.f, ss = 0.f;
#pragma unroll
  for (int i = 0; i < 8; i++) {
    float4 v = xv[threadIdx.x + i * 256];
    s  += v.x + v.y + v.z + v.w;
    ss += v.x * v.x + v.y * v.y + v.z * v.z + v.w * v.w;
  }
#pragma unroll
  for (int off = 32; off; off >>= 1) { s += __shfl_down(s, off); ss += __shfl_down(ss, off); }
  int wv = threadIdx.x >> 6;
  if ((threadIdx.x & 63) == 0) { ls[wv] = s; lss[wv] = ss; }
  __syncthreads();
  if (threadIdx.x == 0) {
    part[blk * 2]     = ls[0] + ls[1] + ls[2] + ls[3];
    part[blk * 2 + 1] = lss[0] + lss[1] + lss[2] + lss[3];
  }
}

// ---------------- 4. normalize + affine + transpose -> xnT[t][b][p][c] bf16 ----------------
// (ln finalize folded in: wave 0 reduces this (t,b)'s 64 partial pairs)
__global__ __launch_bounds__(256) void k_norm_t(
    const float* __restrict__ image, const float* __restrict__ watermark,
    const float* __restrict__ img_w, const float* __restrict__ img_b,
    const float* __restrict__ wm_w,  const float* __restrict__ wm_b,
    const float* __restrict__ part, __hip_bfloat16* __restrict__ xnT)
{
  int blk = blockIdx.x;
  int ct = blk & 15, pt = (blk >> 4) & 15, b = (blk >> 8) & 15, t = blk >> 12;
  int c0 = ct * 32, p0 = pt * 64;
  const float* x   = (t ? watermark : image) + (size_t)b * Cch * HWp;
  const float* wgt = t ? wm_w : img_w;
  const float* bia = t ? wm_b : img_b;
  int tid = threadIdx.x;
  __shared__ float sst[2];
  if (tid < 64) {
    float S  = part[(t * 1024 + b * 64 + tid) * 2];
    float SS = part[(t * 1024 + b * 64 + tid) * 2 + 1];
#pragma unroll
    for (int off = 32; off; off >>= 1) { S += __shfl_down(S, off); SS += __shfl_down(SS, off); }
    if (tid == 0) {
      const float inv = 1.f / (float)(Cch * HWp);
      float mu  = S * inv;
      float var = SS * inv - mu * mu;
      sst[0] = mu;
      sst[1] = rsqrtf(var + 1e-5f);
    }
  }
  __syncthreads();
  float mu = sst[0], rstd = sst[1];
  __shared__ float tile[32 * 66];
  {
    int c = tid >> 3, s = tid & 7;
    const float* xr = x   + (size_t)(c0 + c) * HWp + p0;
    const float* wr = wgt + (size_t)(c0 + c) * HWp + p0;
    const float* br = bia + (size_t)(c0 + c) * HWp + p0;
#pragma unroll
    for (int j = 0; j < 2; j++) {
      int f = s + j * 8;                 // float4 slot 0..15
      float4 xv = *(const float4*)&xr[f * 4];
      float4 wv = *(const float4*)&wr[f * 4];
      float4 bv = *(const float4*)&br[f * 4];
      float n0 = (xv.x - mu) * rstd * wv.x + bv.x;
      float n1 = (xv.y - mu) * rstd * wv.y + bv.y;
      float n2 = (xv.z - mu) * rstd * wv.z + bv.z;
      float n3 = (xv.w - mu) * rstd * wv.w + bv.w;
      *(float2*)&tile[c * 66 + f * 4]     = make_float2(n0, n1);
      *(float2*)&tile[c * 66 + f * 4 + 2] = make_float2(n2, n3);
    }
  }
  __syncthreads();
  {
    int p = tid >> 2, cq = tid & 3;      // 64 p x 4 c-groups of 8
    union { unsigned short us[8]; uint4 v4; } pk;
#pragma unroll
    for (int j = 0; j < 8; j++) pk.us[j] = f2bf(tile[(cq * 8 + j) * 66 + p]);
    __hip_bfloat16* dst = xnT + ((size_t)(t * 16 + b)) * HWp * Cch
                        + (size_t)(p0 + p) * Cch + c0 + cq * 8;
    *(uint4*)dst = pk.v4;
  }
}

// ---------------- 5. bf16 BT-GEMM core: 16x16x32 MFMA + XOR-swizzled LDS ----------------
template<int MI, int Kdim, int Ncols, bool OBF, bool HB>
DEV void gemm_core(const __hip_bfloat16* __restrict__ A,
                   const __hip_bfloat16* __restrict__ Bt,
                   const float* __restrict__ bias, void* __restrict__ Cout, int m0)
{
  constexpr int MT = MI * 32;
  __shared__ __hip_bfloat16 As[MT * 64];
  __shared__ __hip_bfloat16 Bs[128 * 64];
  const int tid = threadIdx.x, lane = tid & 63, wv = tid >> 6;
  const int lr = lane & 15, lq = lane >> 4;
  const int wm = (wv >> 1) * (MI * 16), wn = (wv & 1) * 64;
  const int n0 = blockIdx.x * 128;
  f32x4 acc[MI][4] = {};
  const int srow = tid >> 3, sslot = tid & 7;
  const int sseg = (sslot ^ (srow & 7)) * 8;    // swizzled global segment (halfs)
  for (int k0 = 0; k0 < Kdim; k0 += 64) {
#pragma unroll
    for (int c = 0; c < MI; c++) {
      int row = srow + c * 32;                  // row&7 == srow&7 (c*32 mult of 8)
      async16(&As[row * 64 + sslot * 8], &A[(size_t)(m0 + row) * Kdim + k0 + sseg]);
    }
#pragma unroll
    for (int c = 0; c < 4; c++) {
      int row = srow + c * 32;
      async16(&Bs[row * 64 + sslot * 8], &Bt[(size_t)(n0 + row) * Kdim + k0 + sseg]);
    }
    __syncthreads();   // compiler emits vmcnt(0) drain here
#pragma unroll
    for (int ks = 0; ks < 2; ks++) {
      bf16x8 af[MI], bfr[4];
#pragma unroll
      for (int mi = 0; mi < MI; mi++) {
        int r = wm + mi * 16 + lr;              // r&7 == lr&7
        af[mi]  = *(const bf16x8*)&As[r * 64 + (((ks * 4 + lq) ^ (lr & 7)) * 8)];
      }
#pragma unroll
      for (int ni = 0; ni < 4; ni++) {
        int r = wn + ni * 16 + lr;
        bfr[ni] = *(const bf16x8*)&Bs[r * 64 + (((ks * 4 + lq) ^ (lr & 7)) * 8)];
      }
#pragma unroll
      for (int mi = 0; mi < MI; mi++)
#pragma unroll
        for (int ni = 0; ni < 4; ni++)
          acc[mi][ni] = __builtin_amdgcn_mfma_f32_16x16x32_bf16(af[mi], bfr[ni], acc[mi][ni], 0, 0, 0);
    }
    __syncthreads();
  }
#pragma unroll
  for (int mi = 0; mi < MI; mi++) {
    int mrow = m0 + wm + mi * 16 + lq * 4;
#pragma unroll
    for (int ni = 0; ni < 4; ni++) {
      int ncol = n0 + wn + ni * 16 + lr;
#pragma unroll
      for (int r = 0; r < 4; r++) {
        float y = acc[mi][ni][r];
        int row = mrow + r;
        if (HB) y += bias[row];
        if (OBF) ((__hip_bfloat16*)Cout)[(size_t)row * Ncols + ncol] = __float2bfloat16(y);
        else     ((float*)Cout)[(size_t)row * Ncols + ncol] = y;
      }
    }
  }
}

__global__ __launch_bounds__(256) void k_pw_gemm(
    const __hip_bfloat16* __restrict__ Wpw, const __hip_bfloat16* __restrict__ xnT,
    const float* __restrict__ img_pw_b, const float* __restrict__ wm_pw_b,
    __hip_bfloat16* __restrict__ Y)
{
  int bz = blockIdx.z, t = bz >> 4;
  gemm_core<4, 512, 1024, true, true>(
      Wpw + (size_t)t * C3 * Cch,
      xnT + (size_t)bz * HWp * Cch,
      t ? wm_pw_b : img_pw_b,
      Y + (size_t)bz * C3 * HWp,
      blockIdx.y * 128);
}

// proj: MI=2 (64-row tiles) -> 1024 blocks = 4 blocks/CU, 16 waves/CU. The m97
// structure needs >=3 co-resident blocks for TLP to hide the vmcnt drain; MI=4's
// 512-block grid gave only 2/CU. This is the r0-verified configuration.
__global__ __launch_bounds__(256) void k_proj_gemm(
    const __hip_bfloat16* __restrict__ projT, const __hip_bfloat16* __restrict__ attnT,
    float* __restrict__ out)
{
  int b = blockIdx.z;
  gemm_core<2, 1024, 1024, false, false>(
      projT, attnT + (size_t)b * HWp * 1024, nullptr, out + (size_t)b * Cch * HWp,
      blockIdx.y * 64);
}

// ---------------- 6. depthwise 3x3 grouped conv, LDS-staged (verified scalar form) ----------------
__global__ __launch_bounds__(256) void k_dw(
    const __hip_bfloat16* __restrict__ Y,
    const float* __restrict__ img_dw_w, const float* __restrict__ img_dw_b,
    const float* __restrict__ wm_dw_w,  const float* __restrict__ wm_dw_b,
    __hip_bfloat16* __restrict__ QKV)
{
  __shared__ __hip_bfloat16 sm[6 * 1024];   // [glch][px], linear (async dest)
  int blk = blockIdx.x;                     // 8192 = 32 tb x 256 gb
  int gb = blk & 255, tb = blk >> 8;
  int tid = threadIdx.x;
  const __hip_bfloat16* src = Y + ((size_t)tb * C3 + gb * 6) * HWp;  // 6 contiguous ch
#pragma unroll
  for (int s = 0; s < 3; s++) {
    int lin = tid + s * 256;                // 768 x 16B = 12KB
    async16(sm + lin * 8, src + lin * 8);
  }
  __syncthreads();                          // vmcnt(0) drain before barrier

  int gl = __builtin_amdgcn_readfirstlane(tid >> 7);   // wave-uniform (2 waves per gl)
  int t  = tid & 127;
  int w0 = (t & 3) * 8;
  int h  = t >> 2;                          // 0..31
  int g  = gb * 2 + gl;
  int tsel = tb >> 4;
  const float* dww = (tsel ? wm_dw_w : img_dw_w) + g * 81;   // 3 o x 27
  const float* dwb = (tsel ? wm_dw_b : img_dw_b) + g * 3;
  float acc[3][8];
#pragma unroll
  for (int o = 0; o < 3; o++) {
    float bv = dwb[o];
#pragma unroll
    for (int w = 0; w < 8; w++) acc[o][w] = bv;
  }
  const bool mlo = (w0 == 0), mhi = (w0 == 24);
#pragma unroll
  for (int i = 0; i < 3; i++) {
#pragma unroll
    for (int kh = 0; kh < 3; kh++) {
      int hh = h + kh - 1;
      if ((unsigned)hh > 31u) continue;
      const __hip_bfloat16* row = sm + (gl * 3 + i) * 1024 + hh * 32;
      bf16x8 c0 = *(const bf16x8*)(row + w0);          // halfs [w0, w0+8), 16B-aligned
      float v[10];
      const unsigned* cu = (const unsigned*)&c0;
#pragma unroll
      for (int j = 0; j < 4; j++) { unsigned u = cu[j]; v[1 + 2*j] = bflo(u); v[2 + 2*j] = bfhi(u); }
      v[0] = mlo ? 0.f : bf1(*(const unsigned short*)(row + w0 - 1));   // half w0-1
      v[9] = mhi ? 0.f : bf1(*(const unsigned short*)(row + w0 + 8));   // half w0+8
#pragma unroll
      for (int o = 0; o < 3; o++) {
        float wk0 = dww[o*27 + i*9 + kh*3 + 0];
        float wk1 = dww[o*27 + i*9 + kh*3 + 1];
        float wk2 = dww[o*27 + i*9 + kh*3 + 2];
#pragma unroll
        for (int w = 0; w < 8; w++)
          acc[o][w] += v[w] * wk0 + v[w + 1] * wk1 + v[w + 2] * wk2;
      }
    }
  }
#pragma unroll
  for (int o = 0; o < 3; o++) {
    union { unsigned short us[8]; uint4 v4; } pk;
#pragma unroll
    for (int w = 0; w < 8; w++) pk.us[w] = f2bf(acc[o][w]);
    *(uint4*)(QKV + ((size_t)tb * C3 + g * 3 + o) * HWp + h * 32 + w0) = pk.v4;
  }
}

// ---------------- 7. attention scores as staged BT-GEMM + softmax over q ----------------
// 512 thr = 8 waves (2x4 wave grid over the 64x64 tile); verified async16+swizzle
// staging (each thread exactly ONE async16 per buffer: 512 x 16B = 8KB tile).
__global__ __launch_bounds__(512) void k_attn_scores(
    const __hip_bfloat16* __restrict__ QKV, __hip_bfloat16* __restrict__ ATg)
{
  __shared__ __hip_bfloat16 As[64 * 64];    // K-tile
  __shared__ __hip_bfloat16 Bs[64 * 64];    // Q-tile
  __shared__ float S[64][65];               // S[k][q]
  __shared__ __hip_bfloat16 Ash[64][72];    // transposed P[q][k]
  int blk = blockIdx.x, kh = blk & 1, m = (blk >> 1) & 1, bn = blk >> 2;
  int b = bn >> 3, nh = bn & 7;
  int tid = threadIdx.x, lane = tid & 63, wv8 = tid >> 6;
  int lr = lane & 15, lq = lane >> 4;
  const int wm = (wv8 >> 2) * 32, wn = (wv8 & 3) * 16;   // 2x4 wave grid, 32x16/wave
  const __hip_bfloat16* Kbase = QKV + (((size_t)(kh * 16 + b)) * C3 + 512 + nh * 64) * HWp;
  const __hip_bfloat16* Qbase = QKV + (((size_t)(m * 16 + b)) * C3 + nh * 64) * HWp;

  f32x4 acc[2] = {};
  const int srow = tid >> 3, sslot = tid & 7;   // 512 thr: srow 0..63
  const int sseg = (sslot ^ (srow & 7)) * 8;    // swizzled global segment (halfs)
  for (int k0 = 0; k0 < HWp; k0 += 64) {
    async16(&As[srow * 64 + sslot * 8], &Kbase[(size_t)srow * HWp + k0 + sseg]);
    async16(&Bs[srow * 64 + sslot * 8], &Qbase[(size_t)srow * HWp + k0 + sseg]);
    __syncthreads();   // compiler emits vmcnt(0) drain here
#pragma unroll
    for (int ks = 0; ks < 2; ks++) {
      bf16x8 af[2], bfr;
#pragma unroll
      for (int mi = 0; mi < 2; mi++) {
        int r = wm + mi * 16 + lr;              // r&7 == lr&7 (wm,16 mult of 8)
        af[mi]  = *(const bf16x8*)&As[r * 64 + (((ks * 4 + lq) ^ (lr & 7)) * 8)];
      }
      {
        int r = wn + lr;                        // wn mult of 8
        bfr = *(const bf16x8*)&Bs[r * 64 + (((ks * 4 + lq) ^ (lr & 7)) * 8)];
      }
#pragma unroll
      for (int mi = 0; mi < 2; mi++)
        acc[mi] = __builtin_amdgcn_mfma_f32_16x16x32_bf16(af[mi], bfr, acc[mi], 0, 0, 0);
    }
    __syncthreads();
  }
  // C/D layout: row (A=K-channel) = wm+mi*16+lq*4+r, col (B=q) = wn+lr
#pragma unroll
  for (int mi = 0; mi < 2; mi++)
#pragma unroll
    for (int r = 0; r < 4; r++)
      S[wm + mi * 16 + lq * 4 + r][wn + lr] = acc[mi][r];
  __syncthreads();
  // softmax over q (columns) per k row; 8 threads per row, 8 q each
  {
    int k = tid >> 3, qg = tid & 7;
    float v[8], mx = -1e30f;
#pragma unroll
    for (int j = 0; j < 8; j++) { v[j] = S[k][qg * 8 + j]; mx = fmaxf(mx, v[j]); }
    mx = fmaxf(mx, __shfl_xor(mx, 1));
    mx = fmaxf(mx, __shfl_xor(mx, 2));
    mx = fmaxf(mx, __shfl_xor(mx, 4));
    float ssum = 0.f;
#pragma unroll
    for (int j = 0; j < 8; j++) { v[j] = __expf(v[j] - mx); ssum += v[j]; }
    ssum += __shfl_xor(ssum, 1);
    ssum += __shfl_xor(ssum, 2);
    ssum += __shfl_xor(ssum, 4);
    float inv = 1.f / ssum;
#pragma unroll
    for (int j = 0; j < 8; j++) Ash[qg * 8 + j][k] = __float2bfloat16(v[j] * inv);
  }
  __syncthreads();
  __hip_bfloat16* outp = ATg + ((size_t)(bn * 2 + m)) * 64 * 128 + kh * 64;
  {
    int row = tid >> 3, seg = (tid & 7) * 8;
    *(uint4*)&outp[(size_t)row * 128 + seg] = *(const uint4*)&Ash[row][seg];
  }
}

// ---------------- 8. attention output ----------------
// pc split 4->8 (p-chunk 128, ps loop 2): 1024 blocks ~= 3 blocks/CU (52 KB LDS),
// halves the serial per-block {load, transpose, 2 syncs} chain. Index-only change.
__global__ __launch_bounds__(256) void k_attn_out(
    const __hip_bfloat16* __restrict__ QKV, const __hip_bfloat16* __restrict__ ATg,
    __hip_bfloat16* __restrict__ attnT)
{
  int blk = blockIdx.x, pc = blk & 7, bn = blk >> 3, b = bn >> 3, nh = bn & 7;
  int tid = threadIdx.x, lane = tid & 63, wv = tid >> 6;
  int lr = lane & 15, lq = lane >> 4;
  __shared__ __hip_bfloat16 ATs[2][64][136];
  __shared__ __hip_bfloat16 VTs[64][136];
#pragma unroll
  for (int m = 0; m < 2; m++) {
    const __hip_bfloat16* src = ATg + ((size_t)(bn * 2 + m)) * 64 * 128;
#pragma unroll
    for (int s = 0; s < 4; s++) {
      int id = tid + s * 256, row = id >> 4, seg = (id & 15) * 8;
      *(uint4*)&ATs[m][row][seg] = *(const uint4*)&src[row * 128 + seg];
    }
  }
  const int vk0 = (tid >> 3) * 4, vps = (tid & 7) * 8;
  for (int ps = 0; ps < 2; ps++) {
    int p0 = pc * 128 + ps * 64;
    __syncthreads();
    union { uint4 v4; unsigned short us[8]; } ld[4];
#pragma unroll
    for (int j = 0; j < 4; j++) {
      int kk = vk0 + j, tk = kk >> 6, hc = kk & 63;
      ld[j].v4 = *(const uint4*)(QKV +
          (((size_t)(tk * 16 + b)) * C3 + 1024 + nh * 64 + hc) * HWp + p0 + vps);
    }
#pragma unroll
    for (int e = 0; e < 8; e++) {
      uint2 w;
      w.x = (unsigned)ld[0].us[e] | ((unsigned)ld[1].us[e] << 16);
      w.y = (unsigned)ld[2].us[e] | ((unsigned)ld[3].us[e] << 16);
      *(uint2*)&VTs[vps + e][vk0] = w;
    }
    __syncthreads();
#pragma unroll
    for (int m = 0; m < 2; m++) {
      f32x4 oacc[4] = {};
#pragma unroll
      for (int ks = 0; ks < 4; ks++) {
        bf16x8 bv = *(const bf16x8*)&VTs[wv * 16 + lr][ks * 32 + lq * 8];
#pragma unroll
        for (int qt = 0; qt < 4; qt++) {
          bf16x8 av = *(const bf16x8*)&ATs[m][qt * 16 + lr][ks * 32 + lq * 8];
          oacc[qt] = __builtin_amdgcn_mfma_f32_16x16x32_bf16(av, bv, oacc[qt], 0, 0, 0);
        }
      }
#pragma unroll
      for (int qt = 0; qt < 4; qt++) {
        int q = qt * 16 + lq * 4;
        int d = nh * 128 + m * 64 + q;
        int p = p0 + wv * 16 + lr;
        union { unsigned short us[4]; uint2 v2; } pk;
#pragma unroll
        for (int r = 0; r < 4; r++) pk.us[r] = f2bf(oacc[qt][r]);
        *(uint2*)&attnT[((size_t)b * HWp + p) * 1024 + d] = pk.v2;
      }
    }
  }
}

extern "C" void kernel_launch(void* const* d_in, const int* in_sizes, int n_in,
                              void* d_out, int out_size, void* d_ws, size_t ws_size,
                              hipStream_t stream)
{
  (void)in_sizes; (void)n_in; (void)out_size; (void)ws_size;
  const float* image     = (const float*)d_in[0];
  const float* watermark = (const float*)d_in[1];
  const float* img_ln_w  = (const float*)d_in[2];
  const float* img_ln_b  = (const float*)d_in[3];
  const float* wm_ln_w   = (const float*)d_in[4];
  const float* wm_ln_b   = (const float*)d_in[5];
  const float* img_pw_w  = (const float*)d_in[6];
  const float* img_pw_b  = (const float*)d_in[7];
  const float* img_dw_w  = (const float*)d_in[8];
  const float* img_dw_b  = (const float*)d_in[9];
  const float* wm_pw_w   = (const float*)d_in[10];
  const float* wm_pw_b   = (const float*)d_in[11];
  const float* wm_dw_w   = (const float*)d_in[12];
  const float* wm_dw_b   = (const float*)d_in[13];
  const float* proj      = (const float*)d_in[14];

  char* ws = (char*)d_ws;
  // workspace map (high-water ~232 MiB); aliases are lifetime-disjoint:
  //   attnT aliases xnT (xnT dead after k_pw_gemm); ATg aliases Y (Y dead after k_dw)
  __hip_bfloat16* Wpw    = (__hip_bfloat16*)(ws + 0);            // 3.0 MiB
  __hip_bfloat16* projT  = (__hip_bfloat16*)(ws + 3145728);      // 1.0 MiB
  float*          lnpart = (float*)(ws + 4194304);               // 16 KiB
  __hip_bfloat16* xnT    = (__hip_bfloat16*)(ws + 5242880);      // 32 MiB
  __hip_bfloat16* attnT  = xnT;                                  // alias
  __hip_bfloat16* Y      = (__hip_bfloat16*)(ws + 41943040);     // 96 MiB
  __hip_bfloat16* ATg    = Y;                                    // alias (4 MiB)
  __hip_bfloat16* QKV    = (__hip_bfloat16*)(ws + 142606336);    // 96 MiB

  k_prep_ln<<<5632, 256, 0, stream>>>(img_pw_w, wm_pw_w, proj, image, watermark,
                                      Wpw, projT, lnpart);
  k_norm_t<<<8192, 256, 0, stream>>>(image, watermark, img_ln_w, img_ln_b,
                                     wm_ln_w, wm_ln_b, lnpart, xnT);
  dim3 gpw(8, 12, 32);
  k_pw_gemm<<<gpw, 256, 0, stream>>>(Wpw, xnT, img_pw_b, wm_pw_b, Y);
  k_dw<<<8192, 256, 0, stream>>>(Y, img_dw_w, img_dw_b, wm_dw_w, wm_dw_b, QKV);
  k_attn_scores<<<512, 512, 0, stream>>>(QKV, ATg);
  k_attn_out<<<1024, 256, 0, stream>>>(QKV, ATg, attnT);
  dim3 gpj(8, 8, 16);
  k_proj_gemm<<<gpj, 256, 0, stream>>>(projT, attnT, (float*)d_out);
}